// Round 4
// baseline (3310.794 us; speedup 1.0000x reference)
//
#include <hip/hip_runtime.h>
#include <hip/hip_bf16.h>

#define N_TOK 8192
#define C_DIM 1024
#define FF_DIM 4096
#define NE 4
#define ROWS_MAX 17408           // max padded packed rows (16384 + 4*256 slack)
#define TOTB256 68               // ROWS_MAX / 256

typedef __attribute__((ext_vector_type(8))) short bf16x8;
typedef __attribute__((ext_vector_type(4))) float f32x4;

__device__ __forceinline__ unsigned short f2bf(float f) {
    union { float f; unsigned int u; } v; v.f = f;
    return (unsigned short)((v.u + 0x7FFFu + ((v.u >> 16) & 1u)) >> 16);
}
__device__ __forceinline__ float bf2f(unsigned short u) {
    union { unsigned int u; float f; } v; v.u = ((unsigned int)u) << 16;
    return v.f;
}

__device__ __forceinline__ void gload_lds16(const void* g, void* l) {
    __builtin_amdgcn_global_load_lds(
        (const __attribute__((address_space(1))) unsigned int*)g,
        (__attribute__((address_space(3))) unsigned int*)l, 16, 0, 0);
}

#define WAITV(N) do { asm volatile("s_waitcnt vmcnt(" #N ")" ::: "memory"); __builtin_amdgcn_sched_barrier(0); } while (0)
#define WAITL0()  do { asm volatile("s_waitcnt lgkmcnt(0)" ::: "memory"); __builtin_amdgcn_sched_barrier(0); } while (0)
#define BAR()     do { __builtin_amdgcn_s_barrier(); __builtin_amdgcn_sched_barrier(0); } while (0)
#define PRIO1()   __builtin_amdgcn_s_setprio(1)
#define PRIO0()   __builtin_amdgcn_s_setprio(0)

// bijective XCD-aware block swizzle (m204): contiguous id-chunks per XCD (k_down)
__device__ __forceinline__ int2 xcd_swz(int gx, int gy) {
    int wg = blockIdx.y * gx + blockIdx.x;
    int nwg = gx * gy;
    int q = nwg >> 3, r = nwg & 7;
    int xcd = wg & 7, idx = wg >> 3;
    int swz = (xcd < r) ? (xcd * (q + 1) + idx) : (r * (q + 1) + (xcd - r) * q + idx);
    return make_int2(swz % gx, swz / gx);
}

// gateup strip swizzle (gx==32 only): each XCD owns a 4-bx column strip; its
// concurrent blocks form 4bx x Nby -> B working set L2-resident.
__device__ __forceinline__ int2 strip_swz32() {
    int wg = blockIdx.y * 32 + blockIdx.x;
    int xcd = wg & 7, idx = wg >> 3;
    int bx = xcd * 4 + (idx & 3);
    int by = (idx >> 4) * 4 + ((idx >> 2) & 3);
    return make_int2(bx, by);
}

// ------- transpose+convert: src fp32 [z][R][S] -> dst bf16 [z][S][R]
__global__ void k_tconv(const float* __restrict__ src0, unsigned short* __restrict__ dst0,
                        int R, int S, size_t dz, int perm, int guoff) {
    __shared__ float tile[64][65];
    const float* src = src0 + (size_t)blockIdx.z * R * S;
    unsigned short* dst = dst0 + (size_t)blockIdx.z * dz;
    const int tc = blockIdx.x * 64;
    const int tr = blockIdx.y * 64;
    const int tid = threadIdx.x;
    const int lr = tid >> 4;          // 0..15
    const int lc4 = (tid & 15) * 4;   // 0..60
    #pragma unroll
    for (int i = 0; i < 64; i += 16) {
        float4 v = *(const float4*)(src + (size_t)(tr + lr + i) * S + tc + lc4);
        tile[lr + i][lc4 + 0] = v.x;
        tile[lr + i][lc4 + 1] = v.y;
        tile[lr + i][lc4 + 2] = v.z;
        tile[lr + i][lc4 + 3] = v.w;
    }
    __syncthreads();
    const int oc = tid >> 4;          // 0..15
    const int r4 = (tid & 15) * 4;    // 0..60
    #pragma unroll
    for (int i = 0; i < 64; i += 16) {
        int cp = tc + oc + i;
        int rowo = perm ? (32 * (cp >> 4) + (cp & 15) + guoff) : cp;
        ushort4 o;
        o.x = f2bf(tile[r4 + 0][oc + i]);
        o.y = f2bf(tile[r4 + 1][oc + i]);
        o.z = f2bf(tile[r4 + 2][oc + i]);
        o.w = f2bf(tile[r4 + 3][oc + i]);
        *(ushort4*)(dst + (size_t)rowo * R + tr + r4) = o;
    }
}

// ---------------- router: fp32 logits, softmax, top-2 -> cw[N][4]; also emits xb ----------------
__global__ void k_router(const float* __restrict__ x, const float* __restrict__ wr,
                         float* __restrict__ cw, unsigned short* __restrict__ xb) {
    int wv = threadIdx.x >> 6, lane = threadIdx.x & 63;
    int n = blockIdx.x * 4 + wv;
    const float* xr = x + (size_t)n * C_DIM;
    unsigned short* xbr = xb + (size_t)n * C_DIM;
    const float4* wr4 = (const float4*)wr;
    float p0 = 0.f, p1 = 0.f, p2 = 0.f, p3 = 0.f;
    for (int j = 0; j < C_DIM / 64; ++j) {
        int c = j * 64 + lane;
        float xv = xr[c];
        xbr[c] = f2bf(xv);
        float4 w = wr4[c];
        p0 += xv * w.x; p1 += xv * w.y; p2 += xv * w.z; p3 += xv * w.w;
    }
    #pragma unroll
    for (int off = 32; off > 0; off >>= 1) {
        p0 += __shfl_down(p0, off);
        p1 += __shfl_down(p1, off);
        p2 += __shfl_down(p2, off);
        p3 += __shfl_down(p3, off);
    }
    if (lane == 0) {
        float l[NE] = {p0, p1, p2, p3};
        float mx = fmaxf(fmaxf(l[0], l[1]), fmaxf(l[2], l[3]));
        float e0[NE]; float s = 0.f;
        #pragma unroll
        for (int i = 0; i < NE; ++i) { e0[i] = expf(l[i] - mx); s += e0[i]; }
        #pragma unroll
        for (int i = 0; i < NE; ++i) e0[i] /= s;
        int i1 = 0;
        #pragma unroll
        for (int i = 1; i < NE; ++i) if (e0[i] > e0[i1]) i1 = i;
        int i2 = -1;
        #pragma unroll
        for (int i = 0; i < NE; ++i) { if (i == i1) continue; if (i2 < 0 || e0[i] > e0[i2]) i2 = i; }
        float o[NE] = {0.f, 0.f, 0.f, 0.f};
        o[i1] = e0[i1]; o[i2] = e0[i2];
        *(float4*)(cw + (size_t)n * 4) = make_float4(o[0], o[1], o[2], o[3]);
    }
}

// ---------------- build per-expert token lists (deterministic, token-id order) ----------------
__global__ void k_build(const float* __restrict__ cw, int* __restrict__ rowlist,
                        float* __restrict__ cwg, int* __restrict__ pos2, int* __restrict__ meta) {
    __shared__ int lcnt[256][NE];
    int tid = threadIdx.x;
    int t0 = tid * 32;
    int c[NE] = {0, 0, 0, 0};
    for (int i = 0; i < 32; ++i) {
        const float* w = cw + (size_t)(t0 + i) * NE;
        #pragma unroll
        for (int e = 0; e < NE; ++e) if (w[e] > 0.f) c[e]++;
    }
    #pragma unroll
    for (int e = 0; e < NE; ++e) lcnt[tid][e] = c[e];
    __syncthreads();
    if (tid == 0) {
        int tot[NE] = {0, 0, 0, 0};
        for (int i = 0; i < 256; ++i)
            #pragma unroll
            for (int e = 0; e < NE; ++e) { int v = lcnt[i][e]; lcnt[i][e] = tot[e]; tot[e] += v; }
        int off = 0;
        #pragma unroll
        for (int e = 0; e < NE; ++e) {
            meta[e] = tot[e];
            int p = (tot[e] + 255) & ~255;
            meta[4 + e] = p;
            meta[8 + e] = off;
            off += p;
        }
        meta[12] = off;
    }
    __syncthreads();
    int pos[NE];
    #pragma unroll
    for (int e = 0; e < NE; ++e) pos[e] = lcnt[tid][e];
    for (int i = 0; i < 32; ++i) {
        int t = t0 + i;
        const float* w = cw + (size_t)t * NE;
        int sl = 0;
        #pragma unroll
        for (int e = 0; e < NE; ++e) if (w[e] > 0.f) {
            int p = meta[8 + e] + pos[e]++;
            rowlist[p] = t;
            cwg[p] = w[e];
            pos2[t * 2 + sl] = p;
            sl++;
        }
    }
    __syncthreads();
    if (tid < NE) {
        int e = tid;
        for (int p = meta[e]; p < meta[4 + e]; ++p) {
            rowlist[meta[8 + e] + p] = 0;
            cwg[meta[8 + e] + p] = 0.f;
        }
    }
}

// ================= shared GEMM fragment macros =================
// 8 waves (2M x 4N), wave tile 128x64 (acc[8][4]). Unit slot = operand x
// 32-k half-K-tile, k-plane layout [4][256][8], SLOT_E elems (16 KB).
#define SLOT_E 8192

#define STAGE_U(P0, P1, slot, kofs) do { \
    gload_lds16((P0) + (kofs), smem + (slot) * SLOT_E + dc0); \
    gload_lds16((P1) + (kofs), smem + (slot) * SLOT_E + dc1); } while (0)
#define STG_A(slot, kofs) STAGE_U(aptr0, aptr1, slot, kofs)
#define STG_B(slot, kofs) STAGE_U(bptr0, bptr1, slot, kofs)

#define LDAL(bk, s) do { _Pragma("unroll") \
    for (int m_ = 0; m_ < 4; ++m_) af[bk][m_] = *(const bf16x8*)&smem[(s) * SLOT_E + rdA + m_ * 128]; } while (0)
#define LDAH(bk, s) do { _Pragma("unroll") \
    for (int m_ = 0; m_ < 4; ++m_) af[bk][m_] = *(const bf16x8*)&smem[(s) * SLOT_E + rdA + (4 + m_) * 128]; } while (0)
#define LDB_(bk, s) do { _Pragma("unroll") \
    for (int n_ = 0; n_ < 4; ++n_) bv[bk][n_] = *(const bf16x8*)&smem[(s) * SLOT_E + rdB + n_ * 128]; } while (0)

#define MMLO(ab, bb) do { _Pragma("unroll") \
    for (int m_ = 0; m_ < 4; ++m_) \
        _Pragma("unroll") \
        for (int n_ = 0; n_ < 4; ++n_) \
            acc[m_][n_] = __builtin_amdgcn_mfma_f32_16x16x32_bf16(af[ab][m_], bv[bb][n_], acc[m_][n_], 0, 0, 0); } while (0)
#define MMHI(ab, bb) do { _Pragma("unroll") \
    for (int m_ = 0; m_ < 4; ++m_) \
        _Pragma("unroll") \
        for (int n_ = 0; n_ < 4; ++n_) \
            acc[4 + m_][n_] = __builtin_amdgcn_mfma_f32_16x16x32_bf16(af[ab][m_], bv[bb][n_], acc[4 + m_][n_], 0, 0, 0); } while (0)

// ---------- k_gateup core: 4 rotating slots (64 KiB LDS -> 2 blocks/CU) ----------
// Per 32-k halftile: {E: read A-lo + B of cur pair, stage next-A; bar; lgkm0;
// 16 MFMA; bar} {O: read A-hi, stage next-B; bar; lgkm0; 16 MFMA; vmcnt(0); bar}.
// Staged pair consumed only after its own vmcnt(0)+bar; a slot is re-staged
// >=1 full barrier after its last read. The per-halftile full drain is hidden
// by the co-resident second block (TLP), which 128 KiB LDS forbade.
#define SUBE(sA, sB, STG) do { \
    LDAL(0, sA); LDB_(0, sB); STG; BAR(); WAITL0(); \
    PRIO1(); MMLO(0, 0); PRIO0(); BAR(); } while (0)
#define SUBO(sA, STG) do { \
    LDAH(0, sA); STG; BAR(); WAITL0(); \
    PRIO1(); MMHI(0, 0); PRIO0(); WAITV(0); BAR(); } while (0)

// ---------- k_down core: proven 8-slot 8-phase (R1), 128 KiB, 1 block/CU ----------
#define ITER8(kb) do { \
    /* ph0 */ LDAL(0, 0); LDB_(0, 1); STG_A(6, (kb) + 96);  BAR(); WAITL0(); PRIO1(); LDAH(1, 0);              MMLO(0, 0); PRIO0(); BAR(); \
    /* ph1 */                         STG_B(7, (kb) + 96);  BAR(); WAITL0(); PRIO1(); LDAL(0, 2); LDB_(1, 3);  MMHI(1, 0); PRIO0(); BAR(); \
    /* ph2 */                         STG_A(0, (kb) + 128); BAR(); WAITL0(); PRIO1(); LDAH(1, 2);              MMLO(0, 1); PRIO0(); BAR(); \
    /* ph3 */                         STG_B(1, (kb) + 128); BAR(); WAITL0(); PRIO1();                          MMHI(1, 1); PRIO0(); WAITV(4); BAR(); \
    /* ph4 */ LDAL(0, 4); LDB_(0, 5); STG_A(2, (kb) + 160); BAR(); WAITL0(); PRIO1(); LDAH(1, 4);              MMLO(0, 0); PRIO0(); BAR(); \
    /* ph5 */                         STG_B(3, (kb) + 160); BAR(); WAITL0(); PRIO1(); LDAL(0, 6); LDB_(1, 7);  MMHI(1, 0); PRIO0(); BAR(); \
    /* ph6 */                         STG_A(4, (kb) + 192); BAR(); WAITL0(); PRIO1(); LDAH(1, 6);              MMLO(0, 1); PRIO0(); BAR(); \
    /* ph7 */                         STG_B(5, (kb) + 192); BAR(); WAITL0(); PRIO1();                          MMHI(1, 1); PRIO0(); WAITV(4); BAR(); \
} while (0)

#define ITER8_LAST(kb) do { \
    LDAL(0, 0); LDB_(0, 1); STG_A(6, (kb) + 96); BAR(); WAITL0(); PRIO1(); LDAH(1, 0);              MMLO(0, 0); PRIO0(); BAR(); \
                            STG_B(7, (kb) + 96); BAR(); WAITL0(); PRIO1(); LDAL(0, 2); LDB_(1, 3);  MMHI(1, 0); PRIO0(); BAR(); \
                                                 BAR(); WAITL0(); PRIO1(); LDAH(1, 2);              MMLO(0, 1); PRIO0(); BAR(); \
                                                 BAR(); WAITL0(); PRIO1();                          MMHI(1, 1); PRIO0(); WAITV(0); BAR(); \
    LDAL(0, 4); LDB_(0, 5);                      BAR(); WAITL0(); PRIO1(); LDAH(1, 4);              MMLO(0, 0); PRIO0(); BAR(); \
                                                 BAR(); WAITL0(); PRIO1(); LDAL(0, 6); LDB_(1, 7);  MMHI(1, 0); PRIO0(); BAR(); \
                                                 BAR(); WAITL0(); PRIO1(); LDAH(1, 6);              MMLO(0, 1); PRIO0(); BAR(); \
                                                 BAR(); WAITL0(); PRIO1();                          MMHI(1, 1); PRIO0(); BAR(); \
} while (0)

// ---------------- merged gate+up GEMM (gathered A rows), silu epilogue ----------------
__global__ __launch_bounds__(512, 4) void k_gateup(
    const unsigned short* __restrict__ xb,
    const unsigned short* __restrict__ wgut,
    const int* __restrict__ rowlist,
    const int* __restrict__ meta,
    unsigned short* __restrict__ h,
    int cbase)
{
    extern __shared__ unsigned short smem[];
    int2 sb = strip_swz32();
    const int bx = sb.x, by = sb.y;
    const int p0 = cbase + by * 256;
    if (p0 >= meta[12]) return;
    const int e = (p0 >= meta[9]) + (p0 >= meta[10]) + (p0 >= meta[11]);

    const int tid = threadIdx.x;
    const int wid = tid >> 6, lane = tid & 63;
    const int wm = wid >> 2, wn = wid & 3;
    const int lrow = lane & 15, lkq = lane >> 4;

    // staging geometry: wave wid owns chunks 2*wid, 2*wid+1 of each unit.
    const int r0 = 64 * ((2 * wid) & 3) + lane;
    const int ka = (wid >> 1) * 8;
    const int dc0 = (2 * wid) * 512, dc1 = dc0 + 512;

    const unsigned short* aptr0 = xb + (size_t)rowlist[p0 + r0] * C_DIM + ka;
    const unsigned short* aptr1 = xb + (size_t)rowlist[p0 + r0 + 64] * C_DIM + ka;
    const unsigned short* Bb = wgut + (size_t)e * (2 * C_DIM * FF_DIM) + (size_t)(bx * 256) * C_DIM;
    const unsigned short* bptr0 = Bb + (size_t)r0 * C_DIM + ka;
    const unsigned short* bptr1 = Bb + (size_t)(r0 + 64) * C_DIM + ka;

    const int rdA = lkq * 2048 + (wm * 128 + lrow) * 8;
    const int rdB = lkq * 2048 + (wn * 64 + lrow) * 8;

    f32x4 acc[8][4] = {};
    bf16x8 af[2][4], bv[2][4];

    // prologue: halftile 0 into pair {0,1}
    STG_A(0, 0);
    STG_B(1, 0);
    WAITV(0);
    BAR();

    const int NH = C_DIM / 32;             // 32 halftiles
    #pragma unroll 1
    for (int i = 0; i < NH / 2 - 1; ++i) {
        const int ko = 64 * i;
        // halftile 2i   (slots 0,1), stage halftile 2i+1 into {2,3}
        SUBE(0, 1, STG_A(2, ko + 32));
        SUBO(0,    STG_B(3, ko + 32));
        // halftile 2i+1 (slots 2,3), stage halftile 2i+2 into {0,1}
        SUBE(2, 3, STG_A(0, ko + 64));
        SUBO(2,    STG_B(1, ko + 64));
    }
    // halftile NH-2 (slots 0,1), stage last halftile into {2,3}
    SUBE(0, 1, STG_A(2, C_DIM - 32));
    SUBO(0,    STG_B(3, C_DIM - 32));
    // halftile NH-1 (slots 2,3), nothing left to stage
    SUBE(2, 3, (void)0);
    SUBO(2,    (void)0);

    // epilogue: h = silu(gate) * up ; ni pairs (2j,2j+1) -> ff = bx*128 + wn*32 + 16j + lrow
    const int ffb = bx * 128 + wn * 32;
    #pragma unroll
    for (int mi = 0; mi < 8; ++mi) {
        int row = by * 256 + wm * 128 + mi * 16 + lkq * 4;   // chunk-relative h row
        #pragma unroll
        for (int j = 0; j < 2; ++j) {
            int ff = ffb + 16 * j + lrow;
            f32x4 g = acc[mi][2 * j];
            f32x4 u = acc[mi][2 * j + 1];
            #pragma unroll
            for (int r = 0; r < 4; ++r) {
                float gv = g[r];
                float hv = gv / (1.f + __expf(-gv)) * u[r];
                h[(size_t)(row + r) * FF_DIM + ff] = f2bf(hv);
            }
        }
    }
}

// ---------------- down GEMM, proven 8-phase core: yd[p] = cwg[p] * (h @ wd[e]) ----------------
__global__ __launch_bounds__(512, 1) void k_down(
    const unsigned short* __restrict__ h,
    const unsigned short* __restrict__ wdt,
    const float* __restrict__ cwg,
    const int* __restrict__ meta,
    unsigned short* __restrict__ yd,
    int cbase)
{
    extern __shared__ unsigned short smem[];
    int2 sb = xcd_swz(gridDim.x, gridDim.y);
    const int bx = sb.x, by = sb.y;
    const int p0 = cbase + by * 256;
    if (p0 >= meta[12]) return;
    const int e = (p0 >= meta[9]) + (p0 >= meta[10]) + (p0 >= meta[11]);

    const int tid = threadIdx.x;
    const int wid = tid >> 6, lane = tid & 63;
    const int wm = wid >> 2, wn = wid & 3;
    const int lrow = lane & 15, lkq = lane >> 4;

    const int r0 = 64 * ((2 * wid) & 3) + lane;
    const int ka = (wid >> 1) * 8;
    const int dc0 = (2 * wid) * 512, dc1 = dc0 + 512;

    const unsigned short* Ab = h + (size_t)(by * 256) * FF_DIM;   // chunk-relative packed rows
    const unsigned short* aptr0 = Ab + (size_t)r0 * FF_DIM + ka;
    const unsigned short* aptr1 = Ab + (size_t)(r0 + 64) * FF_DIM + ka;
    const unsigned short* Bb = wdt + (size_t)e * (C_DIM * FF_DIM) + (size_t)(bx * 256) * FF_DIM;
    const unsigned short* bptr0 = Bb + (size_t)r0 * FF_DIM + ka;
    const unsigned short* bptr1 = Bb + (size_t)(r0 + 64) * FF_DIM + ka;

    const int rdA = lkq * 2048 + (wm * 128 + lrow) * 8;
    const int rdB = lkq * 2048 + (wn * 64 + lrow) * 8;

    f32x4 acc[8][4] = {};
    bf16x8 af[2][4], bv[2][4];

    STG_A(0, 0);
    STG_B(1, 0);
    STG_A(2, 32);
    STG_B(3, 32);
    STG_A(4, 64);
    STG_B(5, 64);
    WAITV(4);
    BAR();

    const int NI = FF_DIM / 128;           // 32
    #pragma unroll 1
    for (int i = 0; i < NI - 1; ++i) {
        const int kb = 128 * i;
        ITER8(kb);
    }
    ITER8_LAST(128 * (NI - 1));

    // epilogue: yd[p][col] = cwg[p] * acc (pads have cwg=0; rows unread)
    #pragma unroll
    for (int mi = 0; mi < 8; ++mi) {
        int pb = p0 + wm * 128 + mi * 16 + lkq * 4;
        float w4[4];
        #pragma unroll
        for (int r = 0; r < 4; ++r) w4[r] = cwg[pb + r];
        #pragma unroll
        for (int ni = 0; ni < 4; ++ni) {
            int col = bx * 256 + wn * 64 + ni * 16 + lrow;
            f32x4 a = acc[mi][ni];
            #pragma unroll
            for (int r = 0; r < 4; ++r)
                yd[(size_t)(pb + r) * C_DIM + col] = f2bf(w4[r] * a[r]);
        }
    }
}

// ---------------- combine: out[t] = yd[slotA] + yd[slotB] (deterministic) ----------------
__global__ void k_combine(const unsigned short* __restrict__ yd, const int* __restrict__ pos2,
                          float* __restrict__ out) {
    int t = blockIdx.x;
    int c4 = threadIdx.x * 4;
    int pA = pos2[t * 2], pB = pos2[t * 2 + 1];
    ushort4 a = *(const ushort4*)(yd + (size_t)pA * C_DIM + c4);
    ushort4 b = *(const ushort4*)(yd + (size_t)pB * C_DIM + c4);
    float4 o;
    o.x = bf2f(a.x) + bf2f(b.x);
    o.y = bf2f(a.y) + bf2f(b.y);
    o.z = bf2f(a.z) + bf2f(b.z);
    o.w = bf2f(a.w) + bf2f(b.w);
    *(float4*)(out + (size_t)t * C_DIM + c4) = o;
}

extern "C" void kernel_launch(void* const* d_in, const int* in_sizes, int n_in,
                              void* d_out, int out_size, void* d_ws, size_t ws_size,
                              hipStream_t stream) {
    (void)in_sizes; (void)n_in; (void)out_size;
    const float* x   = (const float*)d_in[0];
    const float* w_r = (const float*)d_in[1];
    const float* w_g = (const float*)d_in[2];
    const float* w_u = (const float*)d_in[3];
    const float* w_d = (const float*)d_in[4];
    float* out = (float*)d_out;

    char* ws = (char*)d_ws;
    unsigned short* xb   = (unsigned short*)(ws);                    // 16,777,216
    unsigned short* wgut = (unsigned short*)(ws + 16777216);         // 67,108,864
    unsigned short* wdt  = (unsigned short*)(ws + 83886080);         // 33,554,432
    unsigned short* yd   = (unsigned short*)(ws + 117440512);        // 35,651,584 (17408 x 1024)
    float*          cw   = (float*)(ws + 153092096);                 //    131,072
    int*            rowlist = (int*)(ws + 153223168);                //     69,632
    float*          cwg  = (float*)(ws + 153292800);                 //     69,632
    int*            pos2 = (int*)(ws + 153362432);                   //     65,536
    int*            meta = (int*)(ws + 153427968);                   //        512
    unsigned short* h    = (unsigned short*)(ws + 153428480);        // chunked: 2 MiB / 256-row block

    hipFuncSetAttribute((const void*)k_gateup, hipFuncAttributeMaxDynamicSharedMemorySize, 4 * SLOT_E * 2);
    hipFuncSetAttribute((const void*)k_down,   hipFuncAttributeMaxDynamicSharedMemorySize, 8 * SLOT_E * 2);

    size_t h_avail = ws_size > 153428480 ? ws_size - 153428480 : 0;
    int maxb = (int)(h_avail / (256 * FF_DIM * 2));   // 2 MiB per 256-row block
    if (maxb < 1) maxb = 1;
    if (maxb > TOTB256) maxb = TOTB256;
    int nch = (TOTB256 + maxb - 1) / maxb;

    k_router<<<N_TOK / 4, 256, 0, stream>>>(x, w_r, cw, xb);
    k_build<<<1, 256, 0, stream>>>(cw, rowlist, cwg, pos2, meta);

    k_tconv<<<dim3(FF_DIM / 64, C_DIM / 64, NE), 256, 0, stream>>>(w_g, wgut, C_DIM, FF_DIM, (size_t)2 * C_DIM * FF_DIM, 1, 0);
    k_tconv<<<dim3(FF_DIM / 64, C_DIM / 64, NE), 256, 0, stream>>>(w_u, wgut, C_DIM, FF_DIM, (size_t)2 * C_DIM * FF_DIM, 1, 16);
    k_tconv<<<dim3(C_DIM / 64, FF_DIM / 64, NE), 256, 0, stream>>>(w_d, wdt, FF_DIM, C_DIM, (size_t)C_DIM * FF_DIM, 0, 0);

    for (int c = 0; c < nch; ++c) {
        int cb = c * maxb;
        int nb = (TOTB256 - cb) < maxb ? (TOTB256 - cb) : maxb;
        k_gateup<<<dim3(2 * FF_DIM / 256, nb), 512, 4 * SLOT_E * 2, stream>>>(xb, wgut, rowlist, meta, h, cb * 256);
        k_down<<<dim3(C_DIM / 256, nb), 512, 8 * SLOT_E * 2, stream>>>(h, wdt, cwg, meta, yd, cb * 256);
    }
    k_combine<<<N_TOK, 256, 0, stream>>>(yd, pos2, out);
}

// Round 5
// 959.125 us; speedup vs baseline: 3.4519x; 3.4519x over previous
//
#include <hip/hip_runtime.h>
#include <hip/hip_bf16.h>

#define N_TOK 8192
#define C_DIM 1024
#define FF_DIM 4096
#define NE 4
#define ROWS_MAX 17408           // max padded packed rows (16384 + 4*256 slack)
#define TOTB256 68               // ROWS_MAX / 256

typedef __attribute__((ext_vector_type(8))) short bf16x8;
typedef __attribute__((ext_vector_type(4))) float f32x4;

__device__ __forceinline__ unsigned short f2bf(float f) {
    union { float f; unsigned int u; } v; v.f = f;
    return (unsigned short)((v.u + 0x7FFFu + ((v.u >> 16) & 1u)) >> 16);
}
__device__ __forceinline__ float bf2f(unsigned short u) {
    union { unsigned int u; float f; } v; v.u = ((unsigned int)u) << 16;
    return v.f;
}

__device__ __forceinline__ void gload_lds16(const void* g, void* l) {
    __builtin_amdgcn_global_load_lds(
        (const __attribute__((address_space(1))) unsigned int*)g,
        (__attribute__((address_space(3))) unsigned int*)l, 16, 0, 0);
}

#define WAITV(N) do { asm volatile("s_waitcnt vmcnt(" #N ")" ::: "memory"); __builtin_amdgcn_sched_barrier(0); } while (0)
#define WAITL0()  do { asm volatile("s_waitcnt lgkmcnt(0)" ::: "memory"); __builtin_amdgcn_sched_barrier(0); } while (0)
#define BAR()     do { __builtin_amdgcn_s_barrier(); __builtin_amdgcn_sched_barrier(0); } while (0)
#define PRIO1()   __builtin_amdgcn_s_setprio(1)
#define PRIO0()   __builtin_amdgcn_s_setprio(0)

// bijective XCD-aware block swizzle (m204): contiguous id-chunks per XCD (k_down)
__device__ __forceinline__ int2 xcd_swz(int gx, int gy) {
    int wg = blockIdx.y * gx + blockIdx.x;
    int nwg = gx * gy;
    int q = nwg >> 3, r = nwg & 7;
    int xcd = wg & 7, idx = wg >> 3;
    int swz = (xcd < r) ? (xcd * (q + 1) + idx) : (r * (q + 1) + (xcd - r) * q + idx);
    return make_int2(swz % gx, swz / gx);
}

// gateup strip swizzle (gx==64): each XCD owns an 8-bx column strip; its ~64
// concurrent blocks form 8bx x 8by -> B working set 2 MB (L2-resident).
__device__ __forceinline__ int2 strip_swz64() {
    int wg = blockIdx.y * 64 + blockIdx.x;
    int xcd = wg & 7, idx = wg >> 3;
    int bx = xcd * 8 + (idx & 7);
    int by = idx >> 3;
    return make_int2(bx, by);
}

// ------- transpose+convert: src fp32 [z][R][S] -> dst bf16 [z][S][R]
__global__ void k_tconv(const float* __restrict__ src0, unsigned short* __restrict__ dst0,
                        int R, int S, size_t dz, int perm, int guoff) {
    __shared__ float tile[64][65];
    const float* src = src0 + (size_t)blockIdx.z * R * S;
    unsigned short* dst = dst0 + (size_t)blockIdx.z * dz;
    const int tc = blockIdx.x * 64;
    const int tr = blockIdx.y * 64;
    const int tid = threadIdx.x;
    const int lr = tid >> 4;          // 0..15
    const int lc4 = (tid & 15) * 4;   // 0..60
    #pragma unroll
    for (int i = 0; i < 64; i += 16) {
        float4 v = *(const float4*)(src + (size_t)(tr + lr + i) * S + tc + lc4);
        tile[lr + i][lc4 + 0] = v.x;
        tile[lr + i][lc4 + 1] = v.y;
        tile[lr + i][lc4 + 2] = v.z;
        tile[lr + i][lc4 + 3] = v.w;
    }
    __syncthreads();
    const int oc = tid >> 4;          // 0..15
    const int r4 = (tid & 15) * 4;    // 0..60
    #pragma unroll
    for (int i = 0; i < 64; i += 16) {
        int cp = tc + oc + i;
        int rowo = perm ? (32 * (cp >> 4) + (cp & 15) + guoff) : cp;
        ushort4 o;
        o.x = f2bf(tile[r4 + 0][oc + i]);
        o.y = f2bf(tile[r4 + 1][oc + i]);
        o.z = f2bf(tile[r4 + 2][oc + i]);
        o.w = f2bf(tile[r4 + 3][oc + i]);
        *(ushort4*)(dst + (size_t)rowo * R + tr + r4) = o;
    }
}

// ---------------- router: fp32 logits, softmax, top-2 -> cw[N][4]; also emits xb ----------------
__global__ void k_router(const float* __restrict__ x, const float* __restrict__ wr,
                         float* __restrict__ cw, unsigned short* __restrict__ xb) {
    int wv = threadIdx.x >> 6, lane = threadIdx.x & 63;
    int n = blockIdx.x * 4 + wv;
    const float* xr = x + (size_t)n * C_DIM;
    unsigned short* xbr = xb + (size_t)n * C_DIM;
    const float4* wr4 = (const float4*)wr;
    float p0 = 0.f, p1 = 0.f, p2 = 0.f, p3 = 0.f;
    for (int j = 0; j < C_DIM / 64; ++j) {
        int c = j * 64 + lane;
        float xv = xr[c];
        xbr[c] = f2bf(xv);
        float4 w = wr4[c];
        p0 += xv * w.x; p1 += xv * w.y; p2 += xv * w.z; p3 += xv * w.w;
    }
    #pragma unroll
    for (int off = 32; off > 0; off >>= 1) {
        p0 += __shfl_down(p0, off);
        p1 += __shfl_down(p1, off);
        p2 += __shfl_down(p2, off);
        p3 += __shfl_down(p3, off);
    }
    if (lane == 0) {
        float l[NE] = {p0, p1, p2, p3};
        float mx = fmaxf(fmaxf(l[0], l[1]), fmaxf(l[2], l[3]));
        float e0[NE]; float s = 0.f;
        #pragma unroll
        for (int i = 0; i < NE; ++i) { e0[i] = expf(l[i] - mx); s += e0[i]; }
        #pragma unroll
        for (int i = 0; i < NE; ++i) e0[i] /= s;
        int i1 = 0;
        #pragma unroll
        for (int i = 1; i < NE; ++i) if (e0[i] > e0[i1]) i1 = i;
        int i2 = -1;
        #pragma unroll
        for (int i = 0; i < NE; ++i) { if (i == i1) continue; if (i2 < 0 || e0[i] > e0[i2]) i2 = i; }
        float o[NE] = {0.f, 0.f, 0.f, 0.f};
        o[i1] = e0[i1]; o[i2] = e0[i2];
        *(float4*)(cw + (size_t)n * 4) = make_float4(o[0], o[1], o[2], o[3]);
    }
}

// ---------------- build per-expert token lists (deterministic, token-id order) ----------------
__global__ void k_build(const float* __restrict__ cw, int* __restrict__ rowlist,
                        float* __restrict__ cwg, int* __restrict__ pos2, int* __restrict__ meta) {
    __shared__ int lcnt[256][NE];
    int tid = threadIdx.x;
    int t0 = tid * 32;
    int c[NE] = {0, 0, 0, 0};
    for (int i = 0; i < 32; ++i) {
        const float* w = cw + (size_t)(t0 + i) * NE;
        #pragma unroll
        for (int e = 0; e < NE; ++e) if (w[e] > 0.f) c[e]++;
    }
    #pragma unroll
    for (int e = 0; e < NE; ++e) lcnt[tid][e] = c[e];
    __syncthreads();
    if (tid == 0) {
        int tot[NE] = {0, 0, 0, 0};
        for (int i = 0; i < 256; ++i)
            #pragma unroll
            for (int e = 0; e < NE; ++e) { int v = lcnt[i][e]; lcnt[i][e] = tot[e]; tot[e] += v; }
        int off = 0;
        #pragma unroll
        for (int e = 0; e < NE; ++e) {
            meta[e] = tot[e];
            int p = (tot[e] + 255) & ~255;
            meta[4 + e] = p;
            meta[8 + e] = off;
            off += p;
        }
        meta[12] = off;
    }
    __syncthreads();
    int pos[NE];
    #pragma unroll
    for (int e = 0; e < NE; ++e) pos[e] = lcnt[tid][e];
    for (int i = 0; i < 32; ++i) {
        int t = t0 + i;
        const float* w = cw + (size_t)t * NE;
        int sl = 0;
        #pragma unroll
        for (int e = 0; e < NE; ++e) if (w[e] > 0.f) {
            int p = meta[8 + e] + pos[e]++;
            rowlist[p] = t;
            cwg[p] = w[e];
            pos2[t * 2 + sl] = p;
            sl++;
        }
    }
    __syncthreads();
    if (tid < NE) {
        int e = tid;
        for (int p = meta[e]; p < meta[4 + e]; ++p) {
            rowlist[meta[8 + e] + p] = 0;
            cwg[meta[8 + e] + p] = 0.f;
        }
    }
}

// ================= k_down shared macros: proven 8-slot 8-phase 256x256 core =================
#define SLOT_E 8192

#define STAGE_U(P0, P1, slot, kofs) do { \
    gload_lds16((P0) + (kofs), smem + (slot) * SLOT_E + dc0); \
    gload_lds16((P1) + (kofs), smem + (slot) * SLOT_E + dc1); } while (0)
#define STG_A(slot, kofs) STAGE_U(aptr0, aptr1, slot, kofs)
#define STG_B(slot, kofs) STAGE_U(bptr0, bptr1, slot, kofs)

#define LDAL(bk, s) do { _Pragma("unroll") \
    for (int m_ = 0; m_ < 4; ++m_) af[bk][m_] = *(const bf16x8*)&smem[(s) * SLOT_E + rdA + m_ * 128]; } while (0)
#define LDAH(bk, s) do { _Pragma("unroll") \
    for (int m_ = 0; m_ < 4; ++m_) af[bk][m_] = *(const bf16x8*)&smem[(s) * SLOT_E + rdA + (4 + m_) * 128]; } while (0)
#define LDB_(bk, s) do { _Pragma("unroll") \
    for (int n_ = 0; n_ < 4; ++n_) bv[bk][n_] = *(const bf16x8*)&smem[(s) * SLOT_E + rdB + n_ * 128]; } while (0)

#define MMLO(ab, bb) do { _Pragma("unroll") \
    for (int m_ = 0; m_ < 4; ++m_) \
        _Pragma("unroll") \
        for (int n_ = 0; n_ < 4; ++n_) \
            acc[m_][n_] = __builtin_amdgcn_mfma_f32_16x16x32_bf16(af[ab][m_], bv[bb][n_], acc[m_][n_], 0, 0, 0); } while (0)
#define MMHI(ab, bb) do { _Pragma("unroll") \
    for (int m_ = 0; m_ < 4; ++m_) \
        _Pragma("unroll") \
        for (int n_ = 0; n_ < 4; ++n_) \
            acc[4 + m_][n_] = __builtin_amdgcn_mfma_f32_16x16x32_bf16(af[ab][m_], bv[bb][n_], acc[4 + m_][n_], 0, 0, 0); } while (0)

#define ITER8(kb) do { \
    /* ph0 */ LDAL(0, 0); LDB_(0, 1); STG_A(6, (kb) + 96);  BAR(); WAITL0(); PRIO1(); LDAH(1, 0);              MMLO(0, 0); PRIO0(); BAR(); \
    /* ph1 */                         STG_B(7, (kb) + 96);  BAR(); WAITL0(); PRIO1(); LDAL(0, 2); LDB_(1, 3);  MMHI(1, 0); PRIO0(); BAR(); \
    /* ph2 */                         STG_A(0, (kb) + 128); BAR(); WAITL0(); PRIO1(); LDAH(1, 2);              MMLO(0, 1); PRIO0(); BAR(); \
    /* ph3 */                         STG_B(1, (kb) + 128); BAR(); WAITL0(); PRIO1();                          MMHI(1, 1); PRIO0(); WAITV(4); BAR(); \
    /* ph4 */ LDAL(0, 4); LDB_(0, 5); STG_A(2, (kb) + 160); BAR(); WAITL0(); PRIO1(); LDAH(1, 4);              MMLO(0, 0); PRIO0(); BAR(); \
    /* ph5 */                         STG_B(3, (kb) + 160); BAR(); WAITL0(); PRIO1(); LDAL(0, 6); LDB_(1, 7);  MMHI(1, 0); PRIO0(); BAR(); \
    /* ph6 */                         STG_A(4, (kb) + 192); BAR(); WAITL0(); PRIO1(); LDAH(1, 6);              MMLO(0, 1); PRIO0(); BAR(); \
    /* ph7 */                         STG_B(5, (kb) + 192); BAR(); WAITL0(); PRIO1();                          MMHI(1, 1); PRIO0(); WAITV(4); BAR(); \
} while (0)

#define ITER8_LAST(kb) do { \
    LDAL(0, 0); LDB_(0, 1); STG_A(6, (kb) + 96); BAR(); WAITL0(); PRIO1(); LDAH(1, 0);              MMLO(0, 0); PRIO0(); BAR(); \
                            STG_B(7, (kb) + 96); BAR(); WAITL0(); PRIO1(); LDAL(0, 2); LDB_(1, 3);  MMHI(1, 0); PRIO0(); BAR(); \
                                                 BAR(); WAITL0(); PRIO1(); LDAH(1, 2);              MMLO(0, 1); PRIO0(); BAR(); \
                                                 BAR(); WAITL0(); PRIO1();                          MMHI(1, 1); PRIO0(); WAITV(0); BAR(); \
    LDAL(0, 4); LDB_(0, 5);                      BAR(); WAITL0(); PRIO1(); LDAH(1, 4);              MMLO(0, 0); PRIO0(); BAR(); \
                                                 BAR(); WAITL0(); PRIO1(); LDAL(0, 6); LDB_(1, 7);  MMHI(1, 0); PRIO0(); BAR(); \
                                                 BAR(); WAITL0(); PRIO1(); LDAH(1, 6);              MMLO(0, 1); PRIO0(); BAR(); \
                                                 BAR(); WAITL0(); PRIO1();                          MMHI(1, 1); PRIO0(); BAR(); \
} while (0)

// ================= k_gateup core: 256x128 tile, 2 blocks/CU =================
// 8 waves as 4M x 2N, wave tile 64x64 (acc[4][4] = 64 VGPR -> fits 128/wave cap
// WITHOUT spill; the R4 spill disaster was acc[8][4]=128 + working set > 128).
// LDS = 3 halftile-pairs, pair = A[4][256][8] (16 KB) + B[4][128][8] (8 KB),
// 72 KB total -> 2 blocks/CU (144 <= 160 KiB). Per phase t: read pair t%3,
// stage halftile t+2 into pair (t+2)%3 (3 loads/thread), counted WAITV(3)
// confirms halftile t+1 before the barrier that precedes its read. Co-resident
// block hides the convoy stalls that 1-block/CU exposed.
#define GU_PAIR 12288   // elems per pair (A 8192 + B 4096)

#define GU_STG(pn, KO) do { \
    gload_lds16(aptr0 + (KO), smem + (pn) * GU_PAIR + dcA0); \
    gload_lds16(aptr1 + (KO), smem + (pn) * GU_PAIR + dcA1); \
    gload_lds16(bptr0 + (KO), smem + (pn) * GU_PAIR + 8192 + dcB); } while (0)

#define GU_PH(p, STG, WV) do { \
    _Pragma("unroll") \
    for (int m_ = 0; m_ < 4; ++m_) af[m_] = *(const bf16x8*)&smem[(p) * GU_PAIR + rdA + m_ * 128]; \
    _Pragma("unroll") \
    for (int n_ = 0; n_ < 4; ++n_) bv[n_] = *(const bf16x8*)&smem[(p) * GU_PAIR + 8192 + rdB + n_ * 128]; \
    STG; \
    BAR(); \
    WAITL0(); \
    PRIO1(); \
    _Pragma("unroll") \
    for (int m_ = 0; m_ < 4; ++m_) \
        _Pragma("unroll") \
        for (int n_ = 0; n_ < 4; ++n_) \
            acc[m_][n_] = __builtin_amdgcn_mfma_f32_16x16x32_bf16(af[m_], bv[n_], acc[m_][n_], 0, 0, 0); \
    PRIO0(); \
    WV; \
    BAR(); \
} while (0)

// ---------------- merged gate+up GEMM (gathered A rows), silu epilogue ----------------
__global__ __launch_bounds__(512, 4) void k_gateup(
    const unsigned short* __restrict__ xb,
    const unsigned short* __restrict__ wgut,
    const int* __restrict__ rowlist,
    const int* __restrict__ meta,
    unsigned short* __restrict__ h,
    int cbase)
{
    extern __shared__ unsigned short smem[];
    int2 sb = strip_swz64();
    const int bx = sb.x, by = sb.y;
    const int p0 = cbase + by * 256;
    if (p0 >= meta[12]) return;
    const int e = (p0 >= meta[9]) + (p0 >= meta[10]) + (p0 >= meta[11]);

    const int tid = threadIdx.x;
    const int wid = tid >> 6, lane = tid & 63;
    const int wm = wid >> 1, wn = wid & 1;       // 4M x 2N
    const int lrow = lane & 15, lkq = lane >> 4;

    // A staging: wave wid covers 128 consecutive rows (2 x 64) of kq plane wid>>1.
    const int r0 = 64 * ((2 * wid) & 3) + lane;
    const int kaA = (wid >> 1) * 8;
    const int dcA0 = 1024 * wid, dcA1 = dcA0 + 512;
    // B staging: wave wid covers 64 rows of kq plane wid>>1.
    const int rB0 = 64 * (wid & 1) + lane;
    const int dcB = 512 * wid;

    const unsigned short* aptr0 = xb + (size_t)rowlist[p0 + r0] * C_DIM + kaA;
    const unsigned short* aptr1 = xb + (size_t)rowlist[p0 + r0 + 64] * C_DIM + kaA;
    const unsigned short* Bb = wgut + (size_t)e * (2 * C_DIM * FF_DIM) + (size_t)(bx * 128) * C_DIM;
    const unsigned short* bptr0 = Bb + (size_t)rB0 * C_DIM + kaA;

    const int rdA = lkq * 2048 + (wm * 64 + lrow) * 8;   // A plane stride 256*8
    const int rdB = lkq * 1024 + (wn * 64 + lrow) * 8;   // B plane stride 128*8

    f32x4 acc[4][4] = {};
    bf16x8 af[4], bv[4];

    // prologue: halftiles 0,1 into pairs 0,1
    GU_STG(0, 0);
    GU_STG(1, 32);
    WAITV(3);     // pair 0 complete; pair 1 in flight
    BAR();

    // 32 halftiles: 10 x 3 phases + 2 tail
    #pragma unroll 1
    for (int i = 0; i < 10; ++i) {
        const int kb = 96 * i;
        GU_PH(0, GU_STG(2, kb + 64),  WAITV(3));
        GU_PH(1, GU_STG(0, kb + 96),  WAITV(3));
        GU_PH(2, GU_STG(1, kb + 128), WAITV(3));
    }
    GU_PH(0, (void)0, WAITV(0));   // halftile 30
    GU_PH(1, (void)0, (void)0);    // halftile 31

    // epilogue: h = silu(gate) * up
    // acc[mi][2j],acc[mi][2j+1] -> gate/up of ff group g = wn*2+j
    #pragma unroll
    for (int mi = 0; mi < 4; ++mi) {
        int row = by * 256 + wm * 64 + mi * 16 + lkq * 4;   // chunk-relative h row
        #pragma unroll
        for (int j = 0; j < 2; ++j) {
            int ff = bx * 64 + (wn * 2 + j) * 16 + lrow;
            f32x4 g = acc[mi][2 * j];
            f32x4 u = acc[mi][2 * j + 1];
            #pragma unroll
            for (int r = 0; r < 4; ++r) {
                float gv = g[r];
                float hv = gv / (1.f + __expf(-gv)) * u[r];
                h[(size_t)(row + r) * FF_DIM + ff] = f2bf(hv);
            }
        }
    }
}

// ---------------- down GEMM, proven 8-phase core: yd[p] = cwg[p] * (h @ wd[e]) ----------------
__global__ __launch_bounds__(512, 1) void k_down(
    const unsigned short* __restrict__ h,
    const unsigned short* __restrict__ wdt,
    const float* __restrict__ cwg,
    const int* __restrict__ meta,
    unsigned short* __restrict__ yd,
    int cbase)
{
    extern __shared__ unsigned short smem[];
    int2 sb = xcd_swz(gridDim.x, gridDim.y);
    const int bx = sb.x, by = sb.y;
    const int p0 = cbase + by * 256;
    if (p0 >= meta[12]) return;
    const int e = (p0 >= meta[9]) + (p0 >= meta[10]) + (p0 >= meta[11]);

    const int tid = threadIdx.x;
    const int wid = tid >> 6, lane = tid & 63;
    const int wm = wid >> 2, wn = wid & 3;
    const int lrow = lane & 15, lkq = lane >> 4;

    const int r0 = 64 * ((2 * wid) & 3) + lane;
    const int ka = (wid >> 1) * 8;
    const int dc0 = (2 * wid) * 512, dc1 = dc0 + 512;

    const unsigned short* Ab = h + (size_t)(by * 256) * FF_DIM;   // chunk-relative packed rows
    const unsigned short* aptr0 = Ab + (size_t)r0 * FF_DIM + ka;
    const unsigned short* aptr1 = Ab + (size_t)(r0 + 64) * FF_DIM + ka;
    const unsigned short* Bb = wdt + (size_t)e * (C_DIM * FF_DIM) + (size_t)(bx * 256) * FF_DIM;
    const unsigned short* bptr0 = Bb + (size_t)r0 * FF_DIM + ka;
    const unsigned short* bptr1 = Bb + (size_t)(r0 + 64) * FF_DIM + ka;

    const int rdA = lkq * 2048 + (wm * 128 + lrow) * 8;
    const int rdB = lkq * 2048 + (wn * 64 + lrow) * 8;

    f32x4 acc[8][4] = {};
    bf16x8 af[2][4], bv[2][4];

    STG_A(0, 0);
    STG_B(1, 0);
    STG_A(2, 32);
    STG_B(3, 32);
    STG_A(4, 64);
    STG_B(5, 64);
    WAITV(4);
    BAR();

    const int NI = FF_DIM / 128;           // 32
    #pragma unroll 1
    for (int i = 0; i < NI - 1; ++i) {
        const int kb = 128 * i;
        ITER8(kb);
    }
    ITER8_LAST(128 * (NI - 1));

    // epilogue: yd[p][col] = cwg[p] * acc (pads have cwg=0; rows unread)
    #pragma unroll
    for (int mi = 0; mi < 8; ++mi) {
        int pb = p0 + wm * 128 + mi * 16 + lkq * 4;
        float w4[4];
        #pragma unroll
        for (int r = 0; r < 4; ++r) w4[r] = cwg[pb + r];
        #pragma unroll
        for (int ni = 0; ni < 4; ++ni) {
            int col = bx * 256 + wn * 64 + ni * 16 + lrow;
            f32x4 a = acc[mi][ni];
            #pragma unroll
            for (int r = 0; r < 4; ++r)
                yd[(size_t)(pb + r) * C_DIM + col] = f2bf(w4[r] * a[r]);
        }
    }
}

// ---------------- combine: out[t] = yd[slotA] + yd[slotB] (deterministic) ----------------
__global__ void k_combine(const unsigned short* __restrict__ yd, const int* __restrict__ pos2,
                          float* __restrict__ out) {
    int t = blockIdx.x;
    int c4 = threadIdx.x * 4;
    int pA = pos2[t * 2], pB = pos2[t * 2 + 1];
    ushort4 a = *(const ushort4*)(yd + (size_t)pA * C_DIM + c4);
    ushort4 b = *(const ushort4*)(yd + (size_t)pB * C_DIM + c4);
    float4 o;
    o.x = bf2f(a.x) + bf2f(b.x);
    o.y = bf2f(a.y) + bf2f(b.y);
    o.z = bf2f(a.z) + bf2f(b.z);
    o.w = bf2f(a.w) + bf2f(b.w);
    *(float4*)(out + (size_t)t * C_DIM + c4) = o;
}

extern "C" void kernel_launch(void* const* d_in, const int* in_sizes, int n_in,
                              void* d_out, int out_size, void* d_ws, size_t ws_size,
                              hipStream_t stream) {
    (void)in_sizes; (void)n_in; (void)out_size;
    const float* x   = (const float*)d_in[0];
    const float* w_r = (const float*)d_in[1];
    const float* w_g = (const float*)d_in[2];
    const float* w_u = (const float*)d_in[3];
    const float* w_d = (const float*)d_in[4];
    float* out = (float*)d_out;

    char* ws = (char*)d_ws;
    unsigned short* xb   = (unsigned short*)(ws);                    // 16,777,216
    unsigned short* wgut = (unsigned short*)(ws + 16777216);         // 67,108,864
    unsigned short* wdt  = (unsigned short*)(ws + 83886080);         // 33,554,432
    unsigned short* yd   = (unsigned short*)(ws + 117440512);        // 35,651,584 (17408 x 1024)
    float*          cw   = (float*)(ws + 153092096);                 //    131,072
    int*            rowlist = (int*)(ws + 153223168);                //     69,632
    float*          cwg  = (float*)(ws + 153292800);                 //     69,632
    int*            pos2 = (int*)(ws + 153362432);                   //     65,536
    int*            meta = (int*)(ws + 153427968);                   //        512
    unsigned short* h    = (unsigned short*)(ws + 153428480);        // chunked: 2 MiB / 256-row block

    hipFuncSetAttribute((const void*)k_gateup, hipFuncAttributeMaxDynamicSharedMemorySize, 3 * GU_PAIR * 2);
    hipFuncSetAttribute((const void*)k_down,   hipFuncAttributeMaxDynamicSharedMemorySize, 8 * SLOT_E * 2);

    size_t h_avail = ws_size > 153428480 ? ws_size - 153428480 : 0;
    int maxb = (int)(h_avail / (256 * FF_DIM * 2));   // 2 MiB per 256-row block
    if (maxb < 1) maxb = 1;
    if (maxb > TOTB256) maxb = TOTB256;
    int nch = (TOTB256 + maxb - 1) / maxb;

    k_router<<<N_TOK / 4, 256, 0, stream>>>(x, w_r, cw, xb);
    k_build<<<1, 256, 0, stream>>>(cw, rowlist, cwg, pos2, meta);

    k_tconv<<<dim3(FF_DIM / 64, C_DIM / 64, NE), 256, 0, stream>>>(w_g, wgut, C_DIM, FF_DIM, (size_t)2 * C_DIM * FF_DIM, 1, 0);
    k_tconv<<<dim3(FF_DIM / 64, C_DIM / 64, NE), 256, 0, stream>>>(w_u, wgut, C_DIM, FF_DIM, (size_t)2 * C_DIM * FF_DIM, 1, 16);
    k_tconv<<<dim3(C_DIM / 64, FF_DIM / 64, NE), 256, 0, stream>>>(w_d, wdt, FF_DIM, C_DIM, (size_t)C_DIM * FF_DIM, 0, 0);

    for (int c = 0; c < nch; ++c) {
        int cb = c * maxb;
        int nb = (TOTB256 - cb) < maxb ? (TOTB256 - cb) : maxb;
        k_gateup<<<dim3(2 * FF_DIM / 128, nb), 512, 3 * GU_PAIR * 2, stream>>>(xb, wgut, rowlist, meta, h, cb * 256);
        k_down<<<dim3(C_DIM / 256, nb), 512, 8 * SLOT_E * 2, stream>>>(h, wdt, cwg, meta, yd, cb * 256);
    }
    k_combine<<<N_TOK, 256, 0, stream>>>(yd, pos2, out);
}

// Round 6
// 659.220 us; speedup vs baseline: 5.0223x; 1.4549x over previous
//
#include <hip/hip_runtime.h>
#include <hip/hip_bf16.h>

#define N_TOK 8192
#define C_DIM 1024
#define FF_DIM 4096
#define NE 4
#define ROWS_MAX 17408           // max padded packed rows (16384 + 4*256 slack)
#define TOTB256 68               // ROWS_MAX / 256

typedef __attribute__((ext_vector_type(8))) short bf16x8;
typedef __attribute__((ext_vector_type(4))) float f32x4;

__device__ __forceinline__ unsigned short f2bf(float f) {
    union { float f; unsigned int u; } v; v.f = f;
    return (unsigned short)((v.u + 0x7FFFu + ((v.u >> 16) & 1u)) >> 16);
}
__device__ __forceinline__ float bf2f(unsigned short u) {
    union { unsigned int u; float f; } v; v.u = ((unsigned int)u) << 16;
    return v.f;
}

__device__ __forceinline__ void gload_lds16(const void* g, void* l) {
    __builtin_amdgcn_global_load_lds(
        (const __attribute__((address_space(1))) unsigned int*)g,
        (__attribute__((address_space(3))) unsigned int*)l, 16, 0, 0);
}

#define WAITV(N) do { asm volatile("s_waitcnt vmcnt(" #N ")" ::: "memory"); __builtin_amdgcn_sched_barrier(0); } while (0)
#define WAITL0()  do { asm volatile("s_waitcnt lgkmcnt(0)" ::: "memory"); __builtin_amdgcn_sched_barrier(0); } while (0)
#define BAR()     do { __builtin_amdgcn_s_barrier(); __builtin_amdgcn_sched_barrier(0); } while (0)
#define PRIO1()   __builtin_amdgcn_s_setprio(1)
#define PRIO0()   __builtin_amdgcn_s_setprio(0)

// bijective XCD-aware block swizzle (m204): contiguous id-chunks per XCD (k_down)
__device__ __forceinline__ int2 xcd_swz(int gx, int gy) {
    int wg = blockIdx.y * gx + blockIdx.x;
    int nwg = gx * gy;
    int q = nwg >> 3, r = nwg & 7;
    int xcd = wg & 7, idx = wg >> 3;
    int swz = (xcd < r) ? (xcd * (q + 1) + idx) : (r * (q + 1) + (xcd - r) * q + idx);
    return make_int2(swz % gx, swz / gx);
}

// gateup strip swizzle (gx==32 only): each XCD owns a 4-bx column strip; its 32
// concurrent blocks form 4bx x 8by -> B working set L2-resident.
__device__ __forceinline__ int2 strip_swz32() {
    int wg = blockIdx.y * 32 + blockIdx.x;
    int xcd = wg & 7, idx = wg >> 3;
    int bx = xcd * 4 + (idx & 3);
    int by = (idx >> 4) * 4 + ((idx >> 2) & 3);
    return make_int2(bx, by);
}

// ------- transpose+convert: src fp32 [z][R][S] -> dst bf16 [z][S][R]
__global__ void k_tconv(const float* __restrict__ src0, unsigned short* __restrict__ dst0,
                        int R, int S, size_t dz, int perm, int guoff) {
    __shared__ float tile[64][65];
    const float* src = src0 + (size_t)blockIdx.z * R * S;
    unsigned short* dst = dst0 + (size_t)blockIdx.z * dz;
    const int tc = blockIdx.x * 64;
    const int tr = blockIdx.y * 64;
    const int tid = threadIdx.x;
    const int lr = tid >> 4;          // 0..15
    const int lc4 = (tid & 15) * 4;   // 0..60
    #pragma unroll
    for (int i = 0; i < 64; i += 16) {
        float4 v = *(const float4*)(src + (size_t)(tr + lr + i) * S + tc + lc4);
        tile[lr + i][lc4 + 0] = v.x;
        tile[lr + i][lc4 + 1] = v.y;
        tile[lr + i][lc4 + 2] = v.z;
        tile[lr + i][lc4 + 3] = v.w;
    }
    __syncthreads();
    const int oc = tid >> 4;          // 0..15
    const int r4 = (tid & 15) * 4;    // 0..60
    #pragma unroll
    for (int i = 0; i < 64; i += 16) {
        int cp = tc + oc + i;
        int rowo = perm ? (32 * (cp >> 4) + (cp & 15) + guoff) : cp;
        ushort4 o;
        o.x = f2bf(tile[r4 + 0][oc + i]);
        o.y = f2bf(tile[r4 + 1][oc + i]);
        o.z = f2bf(tile[r4 + 2][oc + i]);
        o.w = f2bf(tile[r4 + 3][oc + i]);
        *(ushort4*)(dst + (size_t)rowo * R + tr + r4) = o;
    }
}

// ---------------- router: fp32 logits, softmax, top-2 -> cw[N][4]; also emits xb ----------------
__global__ void k_router(const float* __restrict__ x, const float* __restrict__ wr,
                         float* __restrict__ cw, unsigned short* __restrict__ xb) {
    int wv = threadIdx.x >> 6, lane = threadIdx.x & 63;
    int n = blockIdx.x * 4 + wv;
    const float* xr = x + (size_t)n * C_DIM;
    unsigned short* xbr = xb + (size_t)n * C_DIM;
    const float4* wr4 = (const float4*)wr;
    float p0 = 0.f, p1 = 0.f, p2 = 0.f, p3 = 0.f;
    for (int j = 0; j < C_DIM / 64; ++j) {
        int c = j * 64 + lane;
        float xv = xr[c];
        xbr[c] = f2bf(xv);
        float4 w = wr4[c];
        p0 += xv * w.x; p1 += xv * w.y; p2 += xv * w.z; p3 += xv * w.w;
    }
    #pragma unroll
    for (int off = 32; off > 0; off >>= 1) {
        p0 += __shfl_down(p0, off);
        p1 += __shfl_down(p1, off);
        p2 += __shfl_down(p2, off);
        p3 += __shfl_down(p3, off);
    }
    if (lane == 0) {
        float l[NE] = {p0, p1, p2, p3};
        float mx = fmaxf(fmaxf(l[0], l[1]), fmaxf(l[2], l[3]));
        float e0[NE]; float s = 0.f;
        #pragma unroll
        for (int i = 0; i < NE; ++i) { e0[i] = expf(l[i] - mx); s += e0[i]; }
        #pragma unroll
        for (int i = 0; i < NE; ++i) e0[i] /= s;
        int i1 = 0;
        #pragma unroll
        for (int i = 1; i < NE; ++i) if (e0[i] > e0[i1]) i1 = i;
        int i2 = -1;
        #pragma unroll
        for (int i = 0; i < NE; ++i) { if (i == i1) continue; if (i2 < 0 || e0[i] > e0[i2]) i2 = i; }
        float o[NE] = {0.f, 0.f, 0.f, 0.f};
        o[i1] = e0[i1]; o[i2] = e0[i2];
        *(float4*)(cw + (size_t)n * 4) = make_float4(o[0], o[1], o[2], o[3]);
    }
}

// ---------------- build per-expert token lists (deterministic, token-id order) ----------------
__global__ void k_build(const float* __restrict__ cw, int* __restrict__ rowlist,
                        float* __restrict__ cwg, int* __restrict__ pos2, int* __restrict__ meta) {
    __shared__ int lcnt[256][NE];
    int tid = threadIdx.x;
    int t0 = tid * 32;
    int c[NE] = {0, 0, 0, 0};
    for (int i = 0; i < 32; ++i) {
        const float* w = cw + (size_t)(t0 + i) * NE;
        #pragma unroll
        for (int e = 0; e < NE; ++e) if (w[e] > 0.f) c[e]++;
    }
    #pragma unroll
    for (int e = 0; e < NE; ++e) lcnt[tid][e] = c[e];
    __syncthreads();
    if (tid == 0) {
        int tot[NE] = {0, 0, 0, 0};
        for (int i = 0; i < 256; ++i)
            #pragma unroll
            for (int e = 0; e < NE; ++e) { int v = lcnt[i][e]; lcnt[i][e] = tot[e]; tot[e] += v; }
        int off = 0;
        #pragma unroll
        for (int e = 0; e < NE; ++e) {
            meta[e] = tot[e];
            int p = (tot[e] + 255) & ~255;
            meta[4 + e] = p;
            meta[8 + e] = off;
            off += p;
        }
        meta[12] = off;
    }
    __syncthreads();
    int pos[NE];
    #pragma unroll
    for (int e = 0; e < NE; ++e) pos[e] = lcnt[tid][e];
    for (int i = 0; i < 32; ++i) {
        int t = t0 + i;
        const float* w = cw + (size_t)t * NE;
        int sl = 0;
        #pragma unroll
        for (int e = 0; e < NE; ++e) if (w[e] > 0.f) {
            int p = meta[8 + e] + pos[e]++;
            rowlist[p] = t;
            cwg[p] = w[e];
            pos2[t * 2 + sl] = p;
            sl++;
        }
    }
    __syncthreads();
    if (tid < NE) {
        int e = tid;
        for (int p = meta[e]; p < meta[4 + e]; ++p) {
            rowlist[meta[8 + e] + p] = 0;
            cwg[meta[8 + e] + p] = 0.f;
        }
    }
}

// ================= 8-phase pipelined 256x256x64 GEMM core (coalesced staging) =================
// Structure identical to the validated R2 core (8 waves 2Mx4N, 8 rotating 16 KB
// unit slots, hoisted reads, WAITV(4) at ph3/ph7). NEW: unit LDS layout is
// row-major [256 rows][32 k] with chunk-XOR swizzle c' = c ^ (row&3) (16B
// chunks). Staging dest stays linear (same dc0/dc1); the global SOURCE is
// remapped so each 4-lane group reads one fully-consumed 64B line:
//   lane l, inst j: row = 32*wid + 16*j + (l>>2), chunk = (l&3) ^ ((l>>2)&3)
// -> 16 L2 requests/instruction instead of 64 (the 2KB-strided per-lane gather
// was saturating L2 request rate: ~20 req/cyc/XCD). Read side applies the same
// involution (lkq ^ (lrow&3)) so fragments receive bit-identical data.
#define SLOT_E 8192   // elems per unit slot

#define STAGE_U(P0, P1, slot, kofs) do { \
    gload_lds16((P0) + (kofs), smem + (slot) * SLOT_E + dc0); \
    gload_lds16((P1) + (kofs), smem + (slot) * SLOT_E + dc1); } while (0)
#define STG_A(slot, kofs) STAGE_U(aptr0, aptr1, slot, kofs)
#define STG_B(slot, kofs) STAGE_U(bptr0, bptr1, slot, kofs)

#define LDAL(bk, s) do { _Pragma("unroll") \
    for (int m_ = 0; m_ < 4; ++m_) af[bk][m_] = *(const bf16x8*)&smem[(s) * SLOT_E + rdA + m_ * 512]; } while (0)
#define LDAH(bk, s) do { _Pragma("unroll") \
    for (int m_ = 0; m_ < 4; ++m_) af[bk][m_] = *(const bf16x8*)&smem[(s) * SLOT_E + rdA + (4 + m_) * 512]; } while (0)
#define LDB_(bk, s) do { _Pragma("unroll") \
    for (int n_ = 0; n_ < 4; ++n_) bv[bk][n_] = *(const bf16x8*)&smem[(s) * SLOT_E + rdB + n_ * 512]; } while (0)

#define MMLO(ab, bb) do { _Pragma("unroll") \
    for (int m_ = 0; m_ < 4; ++m_) \
        _Pragma("unroll") \
        for (int n_ = 0; n_ < 4; ++n_) \
            acc[m_][n_] = __builtin_amdgcn_mfma_f32_16x16x32_bf16(af[ab][m_], bv[bb][n_], acc[m_][n_], 0, 0, 0); } while (0)
#define MMHI(ab, bb) do { _Pragma("unroll") \
    for (int m_ = 0; m_ < 4; ++m_) \
        _Pragma("unroll") \
        for (int n_ = 0; n_ < 4; ++n_) \
            acc[4 + m_][n_] = __builtin_amdgcn_mfma_f32_16x16x32_bf16(af[ab][m_], bv[bb][n_], acc[4 + m_][n_], 0, 0, 0); } while (0)

// Steady-state iteration: staging schedule identical to the validated core.
#define ITER8(kb) do { \
    /* ph0 */ LDAL(0, 0); LDB_(0, 1); STG_A(6, (kb) + 96);  BAR(); WAITL0(); PRIO1(); LDAH(1, 0);              MMLO(0, 0); PRIO0(); BAR(); \
    /* ph1 */                         STG_B(7, (kb) + 96);  BAR(); WAITL0(); PRIO1(); LDAL(0, 2); LDB_(1, 3);  MMHI(1, 0); PRIO0(); BAR(); \
    /* ph2 */                         STG_A(0, (kb) + 128); BAR(); WAITL0(); PRIO1(); LDAH(1, 2);              MMLO(0, 1); PRIO0(); BAR(); \
    /* ph3 */                         STG_B(1, (kb) + 128); BAR(); WAITL0(); PRIO1();                          MMHI(1, 1); PRIO0(); WAITV(4); BAR(); \
    /* ph4 */ LDAL(0, 4); LDB_(0, 5); STG_A(2, (kb) + 160); BAR(); WAITL0(); PRIO1(); LDAH(1, 4);              MMLO(0, 0); PRIO0(); BAR(); \
    /* ph5 */                         STG_B(3, (kb) + 160); BAR(); WAITL0(); PRIO1(); LDAL(0, 6); LDB_(1, 7);  MMHI(1, 0); PRIO0(); BAR(); \
    /* ph6 */                         STG_A(4, (kb) + 192); BAR(); WAITL0(); PRIO1(); LDAH(1, 6);              MMLO(0, 1); PRIO0(); BAR(); \
    /* ph7 */                         STG_B(5, (kb) + 192); BAR(); WAITL0(); PRIO1();                          MMHI(1, 1); PRIO0(); WAITV(4); BAR(); \
} while (0)

// Last iteration: only kb+96 half-tile left to stage; drain at ph3.
#define ITER8_LAST(kb) do { \
    LDAL(0, 0); LDB_(0, 1); STG_A(6, (kb) + 96); BAR(); WAITL0(); PRIO1(); LDAH(1, 0);              MMLO(0, 0); PRIO0(); BAR(); \
                            STG_B(7, (kb) + 96); BAR(); WAITL0(); PRIO1(); LDAL(0, 2); LDB_(1, 3);  MMHI(1, 0); PRIO0(); BAR(); \
                                                 BAR(); WAITL0(); PRIO1(); LDAH(1, 2);              MMLO(0, 1); PRIO0(); BAR(); \
                                                 BAR(); WAITL0(); PRIO1();                          MMHI(1, 1); PRIO0(); WAITV(0); BAR(); \
    LDAL(0, 4); LDB_(0, 5);                      BAR(); WAITL0(); PRIO1(); LDAH(1, 4);              MMLO(0, 0); PRIO0(); BAR(); \
                                                 BAR(); WAITL0(); PRIO1(); LDAL(0, 6); LDB_(1, 7);  MMHI(1, 0); PRIO0(); BAR(); \
                                                 BAR(); WAITL0(); PRIO1(); LDAH(1, 6);              MMLO(0, 1); PRIO0(); BAR(); \
                                                 BAR(); WAITL0(); PRIO1();                          MMHI(1, 1); PRIO0(); BAR(); \
} while (0)

// ---------------- merged gate+up GEMM (gathered A rows), silu epilogue ----------------
__global__ __launch_bounds__(512, 1) void k_gateup(
    const unsigned short* __restrict__ xb,
    const unsigned short* __restrict__ wgut,
    const int* __restrict__ rowlist,
    const int* __restrict__ meta,
    unsigned short* __restrict__ h,
    int cbase)
{
    extern __shared__ unsigned short smem[];
    int2 sb = strip_swz32();
    const int bx = sb.x, by = sb.y;
    const int p0 = cbase + by * 256;
    if (p0 >= meta[12]) return;
    const int e = (p0 >= meta[9]) + (p0 >= meta[10]) + (p0 >= meta[11]);

    const int tid = threadIdx.x;
    const int wid = tid >> 6, lane = tid & 63;
    const int wm = wid >> 2, wn = wid & 3;
    const int lrow = lane & 15, lkq = lane >> 4;

    // coalesced staging geometry: inst j of wave wid covers rows 32*wid+16*j..+15,
    // lane l -> row +(l>>2), swizzled chunk (l&3)^((l>>2)&3).
    const int lsub = lane >> 2;                       // 0..15
    const int kc = ((lane & 3) ^ (lsub & 3)) * 8;     // chunk offset (elems)
    const int row0 = 32 * wid + lsub;
    const int dc0 = wid * 1024, dc1 = dc0 + 512;      // linear dest (unchanged)

    const unsigned short* aptr0 = xb + (size_t)rowlist[p0 + row0] * C_DIM + kc;
    const unsigned short* aptr1 = xb + (size_t)rowlist[p0 + row0 + 16] * C_DIM + kc;
    const unsigned short* Bb = wgut + (size_t)e * (2 * C_DIM * FF_DIM) + (size_t)(bx * 256) * C_DIM;
    const unsigned short* bptr0 = Bb + (size_t)row0 * C_DIM + kc;
    const unsigned short* bptr1 = Bb + (size_t)(row0 + 16) * C_DIM + kc;

    // read side: row-major [256][32] unit + same chunk involution
    const int swz = (lkq ^ (lrow & 3)) * 8;
    const int rdA = (wm * 128 + lrow) * 32 + swz;
    const int rdB = (wn * 64 + lrow) * 32 + swz;

    f32x4 acc[8][4] = {};
    bf16x8 af[2][4], bv[2][4];

    STG_A(0, 0);
    STG_B(1, 0);
    STG_A(2, 32);
    STG_B(3, 32);
    STG_A(4, 64);
    STG_B(5, 64);
    WAITV(4);
    BAR();

    const int NI = C_DIM / 128;            // 8
    #pragma unroll 1
    for (int i = 0; i < NI - 1; ++i) {
        const int kb = 128 * i;
        ITER8(kb);
    }
    ITER8_LAST(128 * (NI - 1));

    // epilogue: h = silu(gate) * up ; ni pairs (2j,2j+1) -> ff = bx*128 + wn*32 + 16j + lrow
    const int ffb = bx * 128 + wn * 32;
    #pragma unroll
    for (int mi = 0; mi < 8; ++mi) {
        int row = by * 256 + wm * 128 + mi * 16 + lkq * 4;   // chunk-relative h row
        #pragma unroll
        for (int j = 0; j < 2; ++j) {
            int ff = ffb + 16 * j + lrow;
            f32x4 g = acc[mi][2 * j];
            f32x4 u = acc[mi][2 * j + 1];
            #pragma unroll
            for (int r = 0; r < 4; ++r) {
                float gv = g[r];
                float hv = gv / (1.f + __expf(-gv)) * u[r];
                h[(size_t)(row + r) * FF_DIM + ff] = f2bf(hv);
            }
        }
    }
}

// ---------------- down GEMM, same core: yd[p] = cwg[p] * (h @ wd[e]) ----------------
__global__ __launch_bounds__(512, 1) void k_down(
    const unsigned short* __restrict__ h,
    const unsigned short* __restrict__ wdt,
    const float* __restrict__ cwg,
    const int* __restrict__ meta,
    unsigned short* __restrict__ yd,
    int cbase)
{
    extern __shared__ unsigned short smem[];
    int2 sb = xcd_swz(gridDim.x, gridDim.y);
    const int bx = sb.x, by = sb.y;
    const int p0 = cbase + by * 256;
    if (p0 >= meta[12]) return;
    const int e = (p0 >= meta[9]) + (p0 >= meta[10]) + (p0 >= meta[11]);

    const int tid = threadIdx.x;
    const int wid = tid >> 6, lane = tid & 63;
    const int wm = wid >> 2, wn = wid & 3;
    const int lrow = lane & 15, lkq = lane >> 4;

    const int lsub = lane >> 2;
    const int kc = ((lane & 3) ^ (lsub & 3)) * 8;
    const int row0 = 32 * wid + lsub;
    const int dc0 = wid * 1024, dc1 = dc0 + 512;

    const unsigned short* Ab = h + (size_t)(by * 256) * FF_DIM;   // chunk-relative packed rows
    const unsigned short* aptr0 = Ab + (size_t)row0 * FF_DIM + kc;
    const unsigned short* aptr1 = Ab + (size_t)(row0 + 16) * FF_DIM + kc;
    const unsigned short* Bb = wdt + (size_t)e * (C_DIM * FF_DIM) + (size_t)(bx * 256) * FF_DIM;
    const unsigned short* bptr0 = Bb + (size_t)row0 * FF_DIM + kc;
    const unsigned short* bptr1 = Bb + (size_t)(row0 + 16) * FF_DIM + kc;

    const int swz = (lkq ^ (lrow & 3)) * 8;
    const int rdA = (wm * 128 + lrow) * 32 + swz;
    const int rdB = (wn * 64 + lrow) * 32 + swz;

    f32x4 acc[8][4] = {};
    bf16x8 af[2][4], bv[2][4];

    STG_A(0, 0);
    STG_B(1, 0);
    STG_A(2, 32);
    STG_B(3, 32);
    STG_A(4, 64);
    STG_B(5, 64);
    WAITV(4);
    BAR();

    const int NI = FF_DIM / 128;           // 32
    #pragma unroll 1
    for (int i = 0; i < NI - 1; ++i) {
        const int kb = 128 * i;
        ITER8(kb);
    }
    ITER8_LAST(128 * (NI - 1));

    // epilogue: yd[p][col] = cwg[p] * acc (pads have cwg=0; rows unread)
    #pragma unroll
    for (int mi = 0; mi < 8; ++mi) {
        int pb = p0 + wm * 128 + mi * 16 + lkq * 4;
        float w4[4];
        #pragma unroll
        for (int r = 0; r < 4; ++r) w4[r] = cwg[pb + r];
        #pragma unroll
        for (int ni = 0; ni < 4; ++ni) {
            int col = bx * 256 + wn * 64 + ni * 16 + lrow;
            f32x4 a = acc[mi][ni];
            #pragma unroll
            for (int r = 0; r < 4; ++r)
                yd[(size_t)(pb + r) * C_DIM + col] = f2bf(w4[r] * a[r]);
        }
    }
}

// ---------------- combine: out[t] = yd[slotA] + yd[slotB] (deterministic) ----------------
__global__ void k_combine(const unsigned short* __restrict__ yd, const int* __restrict__ pos2,
                          float* __restrict__ out) {
    int t = blockIdx.x;
    int c4 = threadIdx.x * 4;
    int pA = pos2[t * 2], pB = pos2[t * 2 + 1];
    ushort4 a = *(const ushort4*)(yd + (size_t)pA * C_DIM + c4);
    ushort4 b = *(const ushort4*)(yd + (size_t)pB * C_DIM + c4);
    float4 o;
    o.x = bf2f(a.x) + bf2f(b.x);
    o.y = bf2f(a.y) + bf2f(b.y);
    o.z = bf2f(a.z) + bf2f(b.z);
    o.w = bf2f(a.w) + bf2f(b.w);
    *(float4*)(out + (size_t)t * C_DIM + c4) = o;
}

extern "C" void kernel_launch(void* const* d_in, const int* in_sizes, int n_in,
                              void* d_out, int out_size, void* d_ws, size_t ws_size,
                              hipStream_t stream) {
    (void)in_sizes; (void)n_in; (void)out_size;
    const float* x   = (const float*)d_in[0];
    const float* w_r = (const float*)d_in[1];
    const float* w_g = (const float*)d_in[2];
    const float* w_u = (const float*)d_in[3];
    const float* w_d = (const float*)d_in[4];
    float* out = (float*)d_out;

    char* ws = (char*)d_ws;
    unsigned short* xb   = (unsigned short*)(ws);                    // 16,777,216
    unsigned short* wgut = (unsigned short*)(ws + 16777216);         // 67,108,864
    unsigned short* wdt  = (unsigned short*)(ws + 83886080);         // 33,554,432
    unsigned short* yd   = (unsigned short*)(ws + 117440512);        // 35,651,584 (17408 x 1024)
    float*          cw   = (float*)(ws + 153092096);                 //    131,072
    int*            rowlist = (int*)(ws + 153223168);                //     69,632
    float*          cwg  = (float*)(ws + 153292800);                 //     69,632
    int*            pos2 = (int*)(ws + 153362432);                   //     65,536
    int*            meta = (int*)(ws + 153427968);                   //        512
    unsigned short* h    = (unsigned short*)(ws + 153428480);        // chunked: 2 MiB / 256-row block

    hipFuncSetAttribute((const void*)k_gateup, hipFuncAttributeMaxDynamicSharedMemorySize, 8 * SLOT_E * 2);
    hipFuncSetAttribute((const void*)k_down,   hipFuncAttributeMaxDynamicSharedMemorySize, 8 * SLOT_E * 2);

    size_t h_avail = ws_size > 153428480 ? ws_size - 153428480 : 0;
    int maxb = (int)(h_avail / (256 * FF_DIM * 2));   // 2 MiB per 256-row block
    if (maxb < 1) maxb = 1;
    if (maxb > TOTB256) maxb = TOTB256;
    int nch = (TOTB256 + maxb - 1) / maxb;

    k_router<<<N_TOK / 4, 256, 0, stream>>>(x, w_r, cw, xb);
    k_build<<<1, 256, 0, stream>>>(cw, rowlist, cwg, pos2, meta);

    k_tconv<<<dim3(FF_DIM / 64, C_DIM / 64, NE), 256, 0, stream>>>(w_g, wgut, C_DIM, FF_DIM, (size_t)2 * C_DIM * FF_DIM, 1, 0);
    k_tconv<<<dim3(FF_DIM / 64, C_DIM / 64, NE), 256, 0, stream>>>(w_u, wgut, C_DIM, FF_DIM, (size_t)2 * C_DIM * FF_DIM, 1, 16);
    k_tconv<<<dim3(C_DIM / 64, FF_DIM / 64, NE), 256, 0, stream>>>(w_d, wdt, FF_DIM, C_DIM, (size_t)C_DIM * FF_DIM, 0, 0);

    for (int c = 0; c < nch; ++c) {
        int cb = c * maxb;
        int nb = (TOTB256 - cb) < maxb ? (TOTB256 - cb) : maxb;
        k_gateup<<<dim3(2 * FF_DIM / 256, nb), 512, 8 * SLOT_E * 2, stream>>>(xb, wgut, rowlist, meta, h, cb * 256);
        k_down<<<dim3(C_DIM / 256, nb), 512, 8 * SLOT_E * 2, stream>>>(h, wdt, cwg, meta, yd, cb * 256);
    }
    k_combine<<<N_TOK, 256, 0, stream>>>(yd, pos2, out);
}

// Round 7
// 641.752 us; speedup vs baseline: 5.1590x; 1.0272x over previous
//
#include <hip/hip_runtime.h>
#include <hip/hip_bf16.h>

#define N_TOK 8192
#define C_DIM 1024
#define FF_DIM 4096
#define NE 4
#define ROWS_MAX 17408           // max padded packed rows (16384 + 4*256 slack)
#define TOTB256 68               // ROWS_MAX / 256

typedef __attribute__((ext_vector_type(8))) short bf16x8;
typedef __attribute__((ext_vector_type(4))) float f32x4;

__device__ __forceinline__ unsigned short f2bf(float f) {
    union { float f; unsigned int u; } v; v.f = f;
    return (unsigned short)((v.u + 0x7FFFu + ((v.u >> 16) & 1u)) >> 16);
}
__device__ __forceinline__ float bf2f(unsigned short u) {
    union { unsigned int u; float f; } v; v.u = ((unsigned int)u) << 16;
    return v.f;
}

__device__ __forceinline__ void gload_lds16(const void* g, void* l) {
    __builtin_amdgcn_global_load_lds(
        (const __attribute__((address_space(1))) unsigned int*)g,
        (__attribute__((address_space(3))) unsigned int*)l, 16, 0, 0);
}

#define WAITV(N) do { asm volatile("s_waitcnt vmcnt(" #N ")" ::: "memory"); __builtin_amdgcn_sched_barrier(0); } while (0)
#define WAITL0()  do { asm volatile("s_waitcnt lgkmcnt(0)" ::: "memory"); __builtin_amdgcn_sched_barrier(0); } while (0)
#define BAR()     do { __builtin_amdgcn_s_barrier(); __builtin_amdgcn_sched_barrier(0); } while (0)
#define PRIO1()   __builtin_amdgcn_s_setprio(1)
#define PRIO0()   __builtin_amdgcn_s_setprio(0)

// bijective XCD-aware block swizzle (m204): contiguous id-chunks per XCD (k_down)
__device__ __forceinline__ int2 xcd_swz(int gx, int gy) {
    int wg = blockIdx.y * gx + blockIdx.x;
    int nwg = gx * gy;
    int q = nwg >> 3, r = nwg & 7;
    int xcd = wg & 7, idx = wg >> 3;
    int swz = (xcd < r) ? (xcd * (q + 1) + idx) : (r * (q + 1) + (xcd - r) * q + idx);
    return make_int2(swz % gx, swz / gx);
}

// gateup strip swizzle (gx==32 only): each XCD owns a 4-bx column strip; its 32
// concurrent blocks form 4bx x 8by -> B working set L2-resident.
__device__ __forceinline__ int2 strip_swz32() {
    int wg = blockIdx.y * 32 + blockIdx.x;
    int xcd = wg & 7, idx = wg >> 3;
    int bx = xcd * 4 + (idx & 3);
    int by = (idx >> 4) * 4 + ((idx >> 2) & 3);
    return make_int2(bx, by);
}

// ------- transpose+convert: src fp32 [z][R][S] -> dst bf16 [z][S][R]
__global__ void k_tconv(const float* __restrict__ src0, unsigned short* __restrict__ dst0,
                        int R, int S, size_t dz, int perm, int guoff) {
    __shared__ float tile[64][65];
    const float* src = src0 + (size_t)blockIdx.z * R * S;
    unsigned short* dst = dst0 + (size_t)blockIdx.z * dz;
    const int tc = blockIdx.x * 64;
    const int tr = blockIdx.y * 64;
    const int tid = threadIdx.x;
    const int lr = tid >> 4;          // 0..15
    const int lc4 = (tid & 15) * 4;   // 0..60
    #pragma unroll
    for (int i = 0; i < 64; i += 16) {
        float4 v = *(const float4*)(src + (size_t)(tr + lr + i) * S + tc + lc4);
        tile[lr + i][lc4 + 0] = v.x;
        tile[lr + i][lc4 + 1] = v.y;
        tile[lr + i][lc4 + 2] = v.z;
        tile[lr + i][lc4 + 3] = v.w;
    }
    __syncthreads();
    const int oc = tid >> 4;          // 0..15
    const int r4 = (tid & 15) * 4;    // 0..60
    #pragma unroll
    for (int i = 0; i < 64; i += 16) {
        int cp = tc + oc + i;
        int rowo = perm ? (32 * (cp >> 4) + (cp & 15) + guoff) : cp;
        ushort4 o;
        o.x = f2bf(tile[r4 + 0][oc + i]);
        o.y = f2bf(tile[r4 + 1][oc + i]);
        o.z = f2bf(tile[r4 + 2][oc + i]);
        o.w = f2bf(tile[r4 + 3][oc + i]);
        *(ushort4*)(dst + (size_t)rowo * R + tr + r4) = o;
    }
}

// ---------------- router: fp32 logits, softmax, top-2 -> cw[N][4]; also emits xb ----------------
__global__ void k_router(const float* __restrict__ x, const float* __restrict__ wr,
                         float* __restrict__ cw, unsigned short* __restrict__ xb) {
    int wv = threadIdx.x >> 6, lane = threadIdx.x & 63;
    int n = blockIdx.x * 4 + wv;
    const float* xr = x + (size_t)n * C_DIM;
    unsigned short* xbr = xb + (size_t)n * C_DIM;
    const float4* wr4 = (const float4*)wr;
    float p0 = 0.f, p1 = 0.f, p2 = 0.f, p3 = 0.f;
    for (int j = 0; j < C_DIM / 64; ++j) {
        int c = j * 64 + lane;
        float xv = xr[c];
        xbr[c] = f2bf(xv);
        float4 w = wr4[c];
        p0 += xv * w.x; p1 += xv * w.y; p2 += xv * w.z; p3 += xv * w.w;
    }
    #pragma unroll
    for (int off = 32; off > 0; off >>= 1) {
        p0 += __shfl_down(p0, off);
        p1 += __shfl_down(p1, off);
        p2 += __shfl_down(p2, off);
        p3 += __shfl_down(p3, off);
    }
    if (lane == 0) {
        float l[NE] = {p0, p1, p2, p3};
        float mx = fmaxf(fmaxf(l[0], l[1]), fmaxf(l[2], l[3]));
        float e0[NE]; float s = 0.f;
        #pragma unroll
        for (int i = 0; i < NE; ++i) { e0[i] = expf(l[i] - mx); s += e0[i]; }
        #pragma unroll
        for (int i = 0; i < NE; ++i) e0[i] /= s;
        int i1 = 0;
        #pragma unroll
        for (int i = 1; i < NE; ++i) if (e0[i] > e0[i1]) i1 = i;
        int i2 = -1;
        #pragma unroll
        for (int i = 0; i < NE; ++i) { if (i == i1) continue; if (i2 < 0 || e0[i] > e0[i2]) i2 = i; }
        float o[NE] = {0.f, 0.f, 0.f, 0.f};
        o[i1] = e0[i1]; o[i2] = e0[i2];
        *(float4*)(cw + (size_t)n * 4) = make_float4(o[0], o[1], o[2], o[3]);
    }
}

// ---------------- build per-expert token lists (deterministic, token-id order) ----------------
__global__ void k_build(const float* __restrict__ cw, int* __restrict__ rowlist,
                        float* __restrict__ cwg, int* __restrict__ pos2, int* __restrict__ meta) {
    __shared__ int lcnt[256][NE];
    int tid = threadIdx.x;
    int t0 = tid * 32;
    int c[NE] = {0, 0, 0, 0};
    for (int i = 0; i < 32; ++i) {
        const float* w = cw + (size_t)(t0 + i) * NE;
        #pragma unroll
        for (int e = 0; e < NE; ++e) if (w[e] > 0.f) c[e]++;
    }
    #pragma unroll
    for (int e = 0; e < NE; ++e) lcnt[tid][e] = c[e];
    __syncthreads();
    if (tid == 0) {
        int tot[NE] = {0, 0, 0, 0};
        for (int i = 0; i < 256; ++i)
            #pragma unroll
            for (int e = 0; e < NE; ++e) { int v = lcnt[i][e]; lcnt[i][e] = tot[e]; tot[e] += v; }
        int off = 0;
        #pragma unroll
        for (int e = 0; e < NE; ++e) {
            meta[e] = tot[e];
            int p = (tot[e] + 255) & ~255;
            meta[4 + e] = p;
            meta[8 + e] = off;
            off += p;
        }
        meta[12] = off;
    }
    __syncthreads();
    int pos[NE];
    #pragma unroll
    for (int e = 0; e < NE; ++e) pos[e] = lcnt[tid][e];
    for (int i = 0; i < 32; ++i) {
        int t = t0 + i;
        const float* w = cw + (size_t)t * NE;
        int sl = 0;
        #pragma unroll
        for (int e = 0; e < NE; ++e) if (w[e] > 0.f) {
            int p = meta[8 + e] + pos[e]++;
            rowlist[p] = t;
            cwg[p] = w[e];
            pos2[t * 2 + sl] = p;
            sl++;
        }
    }
    __syncthreads();
    if (tid < NE) {
        int e = tid;
        for (int p = meta[e]; p < meta[4 + e]; ++p) {
            rowlist[meta[8 + e] + p] = 0;
            cwg[meta[8 + e] + p] = 0.f;
        }
    }
}

// ================= 8-phase pipelined 256x256x64 GEMM core (coalesced staging) =================
// Structure identical to the validated R2 core (8 waves 2Mx4N, 8 rotating 16 KB
// unit slots, hoisted reads, WAITV(4) at ph3/ph7). Unit layout: 16-row granules
// of 1024B; within a granule, position q holds (row_local = q>>2,
// k-chunk = (q&3) ^ ((q>>3)&3)).  Stage (dest linear, position = lane): lane l
// sources row = 32*wid + (l>>2), chunk = (l&3) ^ ((l>>3)&3) -> each 4-lane quad
// reads one fully-consumed 64B line (16 L2 req/inst, the R6 win).  Read: lane
// (lrow,lkq) reads q = 4*lrow + (lkq ^ ((lrow>>1)&3)); for any 8 consecutive
// lanes, (lrow&1,(lrow>>1)&3) sweeps all 8 combos -> q mod 8 covers all 8 bank
// groups exactly once -> ZERO bank conflicts (R6's (lkq^(lrow&3)) reused row
// bit 0, already consumed by 4*lrow, giving 2-way conflicts = 2.1e7 cycles).
#define SLOT_E 8192   // elems per unit slot

#define STAGE_U(P0, P1, slot, kofs) do { \
    gload_lds16((P0) + (kofs), smem + (slot) * SLOT_E + dc0); \
    gload_lds16((P1) + (kofs), smem + (slot) * SLOT_E + dc1); } while (0)
#define STG_A(slot, kofs) STAGE_U(aptr0, aptr1, slot, kofs)
#define STG_B(slot, kofs) STAGE_U(bptr0, bptr1, slot, kofs)

#define LDAL(bk, s) do { _Pragma("unroll") \
    for (int m_ = 0; m_ < 4; ++m_) af[bk][m_] = *(const bf16x8*)&smem[(s) * SLOT_E + rdA + m_ * 512]; } while (0)
#define LDAH(bk, s) do { _Pragma("unroll") \
    for (int m_ = 0; m_ < 4; ++m_) af[bk][m_] = *(const bf16x8*)&smem[(s) * SLOT_E + rdA + (4 + m_) * 512]; } while (0)
#define LDB_(bk, s) do { _Pragma("unroll") \
    for (int n_ = 0; n_ < 4; ++n_) bv[bk][n_] = *(const bf16x8*)&smem[(s) * SLOT_E + rdB + n_ * 512]; } while (0)

#define MMLO(ab, bb) do { _Pragma("unroll") \
    for (int m_ = 0; m_ < 4; ++m_) \
        _Pragma("unroll") \
        for (int n_ = 0; n_ < 4; ++n_) \
            acc[m_][n_] = __builtin_amdgcn_mfma_f32_16x16x32_bf16(af[ab][m_], bv[bb][n_], acc[m_][n_], 0, 0, 0); } while (0)
#define MMHI(ab, bb) do { _Pragma("unroll") \
    for (int m_ = 0; m_ < 4; ++m_) \
        _Pragma("unroll") \
        for (int n_ = 0; n_ < 4; ++n_) \
            acc[4 + m_][n_] = __builtin_amdgcn_mfma_f32_16x16x32_bf16(af[ab][m_], bv[bb][n_], acc[4 + m_][n_], 0, 0, 0); } while (0)

// Steady-state iteration: staging schedule identical to the validated core.
#define ITER8(kb) do { \
    /* ph0 */ LDAL(0, 0); LDB_(0, 1); STG_A(6, (kb) + 96);  BAR(); WAITL0(); PRIO1(); LDAH(1, 0);              MMLO(0, 0); PRIO0(); BAR(); \
    /* ph1 */                         STG_B(7, (kb) + 96);  BAR(); WAITL0(); PRIO1(); LDAL(0, 2); LDB_(1, 3);  MMHI(1, 0); PRIO0(); BAR(); \
    /* ph2 */                         STG_A(0, (kb) + 128); BAR(); WAITL0(); PRIO1(); LDAH(1, 2);              MMLO(0, 1); PRIO0(); BAR(); \
    /* ph3 */                         STG_B(1, (kb) + 128); BAR(); WAITL0(); PRIO1();                          MMHI(1, 1); PRIO0(); WAITV(4); BAR(); \
    /* ph4 */ LDAL(0, 4); LDB_(0, 5); STG_A(2, (kb) + 160); BAR(); WAITL0(); PRIO1(); LDAH(1, 4);              MMLO(0, 0); PRIO0(); BAR(); \
    /* ph5 */                         STG_B(3, (kb) + 160); BAR(); WAITL0(); PRIO1(); LDAL(0, 6); LDB_(1, 7);  MMHI(1, 0); PRIO0(); BAR(); \
    /* ph6 */                         STG_A(4, (kb) + 192); BAR(); WAITL0(); PRIO1(); LDAH(1, 6);              MMLO(0, 1); PRIO0(); BAR(); \
    /* ph7 */                         STG_B(5, (kb) + 192); BAR(); WAITL0(); PRIO1();                          MMHI(1, 1); PRIO0(); WAITV(4); BAR(); \
} while (0)

// Last iteration: only kb+96 half-tile left to stage; drain at ph3.
#define ITER8_LAST(kb) do { \
    LDAL(0, 0); LDB_(0, 1); STG_A(6, (kb) + 96); BAR(); WAITL0(); PRIO1(); LDAH(1, 0);              MMLO(0, 0); PRIO0(); BAR(); \
                            STG_B(7, (kb) + 96); BAR(); WAITL0(); PRIO1(); LDAL(0, 2); LDB_(1, 3);  MMHI(1, 0); PRIO0(); BAR(); \
                                                 BAR(); WAITL0(); PRIO1(); LDAH(1, 2);              MMLO(0, 1); PRIO0(); BAR(); \
                                                 BAR(); WAITL0(); PRIO1();                          MMHI(1, 1); PRIO0(); WAITV(0); BAR(); \
    LDAL(0, 4); LDB_(0, 5);                      BAR(); WAITL0(); PRIO1(); LDAH(1, 4);              MMLO(0, 0); PRIO0(); BAR(); \
                                                 BAR(); WAITL0(); PRIO1(); LDAL(0, 6); LDB_(1, 7);  MMHI(1, 0); PRIO0(); BAR(); \
                                                 BAR(); WAITL0(); PRIO1(); LDAH(1, 6);              MMLO(0, 1); PRIO0(); BAR(); \
                                                 BAR(); WAITL0(); PRIO1();                          MMHI(1, 1); PRIO0(); BAR(); \
} while (0)

// ---------------- merged gate+up GEMM (gathered A rows), silu epilogue ----------------
__global__ __launch_bounds__(512, 1) void k_gateup(
    const unsigned short* __restrict__ xb,
    const unsigned short* __restrict__ wgut,
    const int* __restrict__ rowlist,
    const int* __restrict__ meta,
    unsigned short* __restrict__ h,
    int cbase)
{
    extern __shared__ unsigned short smem[];
    int2 sb = strip_swz32();
    const int bx = sb.x, by = sb.y;
    const int p0 = cbase + by * 256;
    if (p0 >= meta[12]) return;
    const int e = (p0 >= meta[9]) + (p0 >= meta[10]) + (p0 >= meta[11]);

    const int tid = threadIdx.x;
    const int wid = tid >> 6, lane = tid & 63;
    const int wm = wid >> 2, wn = wid & 3;
    const int lrow = lane & 15, lkq = lane >> 4;

    // coalesced staging: inst j of wave wid covers rows 32*wid+16*j..+15;
    // lane l -> row +(l>>2), chunk (l&3)^((l>>3)&3) (quad = one 64B line).
    const int lsub = lane >> 2;                        // 0..15
    const int kc = ((lane & 3) ^ ((lane >> 3) & 3)) * 8;
    const int row0 = 32 * wid + lsub;
    const int dc0 = wid * 1024, dc1 = dc0 + 512;       // linear dest (unchanged)

    const unsigned short* aptr0 = xb + (size_t)rowlist[p0 + row0] * C_DIM + kc;
    const unsigned short* aptr1 = xb + (size_t)rowlist[p0 + row0 + 16] * C_DIM + kc;
    const unsigned short* Bb = wgut + (size_t)e * (2 * C_DIM * FF_DIM) + (size_t)(bx * 256) * C_DIM;
    const unsigned short* bptr0 = Bb + (size_t)row0 * C_DIM + kc;
    const unsigned short* bptr1 = Bb + (size_t)(row0 + 16) * C_DIM + kc;

    // read side: granule (row>>4)*512 elems; q = 4*lrow + (lkq ^ ((lrow>>1)&3))
    const int q8 = (4 * lrow + (lkq ^ ((lrow >> 1) & 3))) * 8;
    const int rdA = wm * 4096 + q8;    // granule base wm*8 * 512
    const int rdB = wn * 2048 + q8;    // granule base wn*4 * 512

    f32x4 acc[8][4] = {};
    bf16x8 af[2][4], bv[2][4];

    STG_A(0, 0);
    STG_B(1, 0);
    STG_A(2, 32);
    STG_B(3, 32);
    STG_A(4, 64);
    STG_B(5, 64);
    WAITV(4);
    BAR();

    const int NI = C_DIM / 128;            // 8
    #pragma unroll 1
    for (int i = 0; i < NI - 1; ++i) {
        const int kb = 128 * i;
        ITER8(kb);
    }
    ITER8_LAST(128 * (NI - 1));

    // epilogue: h = silu(gate) * up ; ni pairs (2j,2j+1) -> ff = bx*128 + wn*32 + 16j + lrow
    const int ffb = bx * 128 + wn * 32;
    #pragma unroll
    for (int mi = 0; mi < 8; ++mi) {
        int row = by * 256 + wm * 128 + mi * 16 + lkq * 4;   // chunk-relative h row
        #pragma unroll
        for (int j = 0; j < 2; ++j) {
            int ff = ffb + 16 * j + lrow;
            f32x4 g = acc[mi][2 * j];
            f32x4 u = acc[mi][2 * j + 1];
            #pragma unroll
            for (int r = 0; r < 4; ++r) {
                float gv = g[r];
                float hv = gv / (1.f + __expf(-gv)) * u[r];
                h[(size_t)(row + r) * FF_DIM + ff] = f2bf(hv);
            }
        }
    }
}

// ---------------- down GEMM, same core: yd[p] = cwg[p] * (h @ wd[e]) ----------------
__global__ __launch_bounds__(512, 1) void k_down(
    const unsigned short* __restrict__ h,
    const unsigned short* __restrict__ wdt,
    const float* __restrict__ cwg,
    const int* __restrict__ meta,
    unsigned short* __restrict__ yd,
    int cbase)
{
    extern __shared__ unsigned short smem[];
    int2 sb = xcd_swz(gridDim.x, gridDim.y);
    const int bx = sb.x, by = sb.y;
    const int p0 = cbase + by * 256;
    if (p0 >= meta[12]) return;
    const int e = (p0 >= meta[9]) + (p0 >= meta[10]) + (p0 >= meta[11]);

    const int tid = threadIdx.x;
    const int wid = tid >> 6, lane = tid & 63;
    const int wm = wid >> 2, wn = wid & 3;
    const int lrow = lane & 15, lkq = lane >> 4;

    const int lsub = lane >> 2;
    const int kc = ((lane & 3) ^ ((lane >> 3) & 3)) * 8;
    const int row0 = 32 * wid + lsub;
    const int dc0 = wid * 1024, dc1 = dc0 + 512;

    const unsigned short* Ab = h + (size_t)(by * 256) * FF_DIM;   // chunk-relative packed rows
    const unsigned short* aptr0 = Ab + (size_t)row0 * FF_DIM + kc;
    const unsigned short* aptr1 = Ab + (size_t)(row0 + 16) * FF_DIM + kc;
    const unsigned short* Bb = wdt + (size_t)e * (C_DIM * FF_DIM) + (size_t)(bx * 256) * FF_DIM;
    const unsigned short* bptr0 = Bb + (size_t)row0 * FF_DIM + kc;
    const unsigned short* bptr1 = Bb + (size_t)(row0 + 16) * FF_DIM + kc;

    const int q8 = (4 * lrow + (lkq ^ ((lrow >> 1) & 3))) * 8;
    const int rdA = wm * 4096 + q8;
    const int rdB = wn * 2048 + q8;

    f32x4 acc[8][4] = {};
    bf16x8 af[2][4], bv[2][4];

    STG_A(0, 0);
    STG_B(1, 0);
    STG_A(2, 32);
    STG_B(3, 32);
    STG_A(4, 64);
    STG_B(5, 64);
    WAITV(4);
    BAR();

    const int NI = FF_DIM / 128;           // 32
    #pragma unroll 1
    for (int i = 0; i < NI - 1; ++i) {
        const int kb = 128 * i;
        ITER8(kb);
    }
    ITER8_LAST(128 * (NI - 1));

    // epilogue: yd[p][col] = cwg[p] * acc (pads have cwg=0; rows unread)
    #pragma unroll
    for (int mi = 0; mi < 8; ++mi) {
        int pb = p0 + wm * 128 + mi * 16 + lkq * 4;
        float w4[4];
        #pragma unroll
        for (int r = 0; r < 4; ++r) w4[r] = cwg[pb + r];
        #pragma unroll
        for (int ni = 0; ni < 4; ++ni) {
            int col = bx * 256 + wn * 64 + ni * 16 + lrow;
            f32x4 a = acc[mi][ni];
            #pragma unroll
            for (int r = 0; r < 4; ++r)
                yd[(size_t)(pb + r) * C_DIM + col] = f2bf(w4[r] * a[r]);
        }
    }
}

// ---------------- combine: out[t] = yd[slotA] + yd[slotB] (deterministic) ----------------
__global__ void k_combine(const unsigned short* __restrict__ yd, const int* __restrict__ pos2,
                          float* __restrict__ out) {
    int t = blockIdx.x;
    int c4 = threadIdx.x * 4;
    int pA = pos2[t * 2], pB = pos2[t * 2 + 1];
    ushort4 a = *(const ushort4*)(yd + (size_t)pA * C_DIM + c4);
    ushort4 b = *(const ushort4*)(yd + (size_t)pB * C_DIM + c4);
    float4 o;
    o.x = bf2f(a.x) + bf2f(b.x);
    o.y = bf2f(a.y) + bf2f(b.y);
    o.z = bf2f(a.z) + bf2f(b.z);
    o.w = bf2f(a.w) + bf2f(b.w);
    *(float4*)(out + (size_t)t * C_DIM + c4) = o;
}

extern "C" void kernel_launch(void* const* d_in, const int* in_sizes, int n_in,
                              void* d_out, int out_size, void* d_ws, size_t ws_size,
                              hipStream_t stream) {
    (void)in_sizes; (void)n_in; (void)out_size;
    const float* x   = (const float*)d_in[0];
    const float* w_r = (const float*)d_in[1];
    const float* w_g = (const float*)d_in[2];
    const float* w_u = (const float*)d_in[3];
    const float* w_d = (const float*)d_in[4];
    float* out = (float*)d_out;

    char* ws = (char*)d_ws;
    unsigned short* xb   = (unsigned short*)(ws);                    // 16,777,216
    unsigned short* wgut = (unsigned short*)(ws + 16777216);         // 67,108,864
    unsigned short* wdt  = (unsigned short*)(ws + 83886080);         // 33,554,432
    unsigned short* yd   = (unsigned short*)(ws + 117440512);        // 35,651,584 (17408 x 1024)
    float*          cw   = (float*)(ws + 153092096);                 //    131,072
    int*            rowlist = (int*)(ws + 153223168);                //     69,632
    float*          cwg  = (float*)(ws + 153292800);                 //     69,632
    int*            pos2 = (int*)(ws + 153362432);                   //     65,536
    int*            meta = (int*)(ws + 153427968);                   //        512
    unsigned short* h    = (unsigned short*)(ws + 153428480);        // chunked: 2 MiB / 256-row block

    hipFuncSetAttribute((const void*)k_gateup, hipFuncAttributeMaxDynamicSharedMemorySize, 8 * SLOT_E * 2);
    hipFuncSetAttribute((const void*)k_down,   hipFuncAttributeMaxDynamicSharedMemorySize, 8 * SLOT_E * 2);

    size_t h_avail = ws_size > 153428480 ? ws_size - 153428480 : 0;
    int maxb = (int)(h_avail / (256 * FF_DIM * 2));   // 2 MiB per 256-row block
    if (maxb < 1) maxb = 1;
    if (maxb > TOTB256) maxb = TOTB256;
    int nch = (TOTB256 + maxb - 1) / maxb;

    k_router<<<N_TOK / 4, 256, 0, stream>>>(x, w_r, cw, xb);
    k_build<<<1, 256, 0, stream>>>(cw, rowlist, cwg, pos2, meta);

    k_tconv<<<dim3(FF_DIM / 64, C_DIM / 64, NE), 256, 0, stream>>>(w_g, wgut, C_DIM, FF_DIM, (size_t)2 * C_DIM * FF_DIM, 1, 0);
    k_tconv<<<dim3(FF_DIM / 64, C_DIM / 64, NE), 256, 0, stream>>>(w_u, wgut, C_DIM, FF_DIM, (size_t)2 * C_DIM * FF_DIM, 1, 16);
    k_tconv<<<dim3(C_DIM / 64, FF_DIM / 64, NE), 256, 0, stream>>>(w_d, wdt, FF_DIM, C_DIM, (size_t)C_DIM * FF_DIM, 0, 0);

    for (int c = 0; c < nch; ++c) {
        int cb = c * maxb;
        int nb = (TOTB256 - cb) < maxb ? (TOTB256 - cb) : maxb;
        k_gateup<<<dim3(2 * FF_DIM / 256, nb), 512, 8 * SLOT_E * 2, stream>>>(xb, wgut, rowlist, meta, h, cb * 256);
        k_down<<<dim3(C_DIM / 256, nb), 512, 8 * SLOT_E * 2, stream>>>(h, wdt, cwg, meta, yd, cb * 256);
    }
    k_combine<<<N_TOK, 256, 0, stream>>>(yd, pos2, out);
}

// Round 8
// 638.717 us; speedup vs baseline: 5.1835x; 1.0048x over previous
//
#include <hip/hip_runtime.h>
#include <hip/hip_bf16.h>

#define N_TOK 8192
#define C_DIM 1024
#define FF_DIM 4096
#define NE 4
#define ROWS_MAX 17408           // max padded packed rows (16384 + 4*256 slack)
#define TOTB256 68               // ROWS_MAX / 256

typedef __attribute__((ext_vector_type(8))) short bf16x8;
typedef __attribute__((ext_vector_type(4))) float f32x4;

__device__ __forceinline__ unsigned short f2bf(float f) {
    union { float f; unsigned int u; } v; v.f = f;
    return (unsigned short)((v.u + 0x7FFFu + ((v.u >> 16) & 1u)) >> 16);
}
__device__ __forceinline__ float bf2f(unsigned short u) {
    union { unsigned int u; float f; } v; v.u = ((unsigned int)u) << 16;
    return v.f;
}

__device__ __forceinline__ void gload_lds16(const void* g, void* l) {
    __builtin_amdgcn_global_load_lds(
        (const __attribute__((address_space(1))) unsigned int*)g,
        (__attribute__((address_space(3))) unsigned int*)l, 16, 0, 0);
}

#define WAITV(N) do { asm volatile("s_waitcnt vmcnt(" #N ")" ::: "memory"); __builtin_amdgcn_sched_barrier(0); } while (0)
#define WAITL0()  do { asm volatile("s_waitcnt lgkmcnt(0)" ::: "memory"); __builtin_amdgcn_sched_barrier(0); } while (0)
#define BAR()     do { __builtin_amdgcn_s_barrier(); __builtin_amdgcn_sched_barrier(0); } while (0)
#define PRIO1()   __builtin_amdgcn_s_setprio(1)
#define PRIO0()   __builtin_amdgcn_s_setprio(0)

// bijective XCD-aware block swizzle (m204): contiguous id-chunks per XCD (k_down)
__device__ __forceinline__ int2 xcd_swz(int gx, int gy) {
    int wg = blockIdx.y * gx + blockIdx.x;
    int nwg = gx * gy;
    int q = nwg >> 3, r = nwg & 7;
    int xcd = wg & 7, idx = wg >> 3;
    int swz = (xcd < r) ? (xcd * (q + 1) + idx) : (r * (q + 1) + (xcd - r) * q + idx);
    return make_int2(swz % gx, swz / gx);
}

// gateup strip swizzle (gx==32 only): each XCD owns a 4-bx column strip; its 32
// concurrent blocks form 4bx x 8by -> B working set L2-resident.
__device__ __forceinline__ int2 strip_swz32() {
    int wg = blockIdx.y * 32 + blockIdx.x;
    int xcd = wg & 7, idx = wg >> 3;
    int bx = xcd * 4 + (idx & 3);
    int by = (idx >> 4) * 4 + ((idx >> 2) & 3);
    return make_int2(bx, by);
}

// ------- transpose+convert: src fp32 [z][R][S] -> dst bf16 [z][S][R]
__global__ void k_tconv(const float* __restrict__ src0, unsigned short* __restrict__ dst0,
                        int R, int S, size_t dz, int perm, int guoff) {
    __shared__ float tile[64][65];
    const float* src = src0 + (size_t)blockIdx.z * R * S;
    unsigned short* dst = dst0 + (size_t)blockIdx.z * dz;
    const int tc = blockIdx.x * 64;
    const int tr = blockIdx.y * 64;
    const int tid = threadIdx.x;
    const int lr = tid >> 4;          // 0..15
    const int lc4 = (tid & 15) * 4;   // 0..60
    #pragma unroll
    for (int i = 0; i < 64; i += 16) {
        float4 v = *(const float4*)(src + (size_t)(tr + lr + i) * S + tc + lc4);
        tile[lr + i][lc4 + 0] = v.x;
        tile[lr + i][lc4 + 1] = v.y;
        tile[lr + i][lc4 + 2] = v.z;
        tile[lr + i][lc4 + 3] = v.w;
    }
    __syncthreads();
    const int oc = tid >> 4;          // 0..15
    const int r4 = (tid & 15) * 4;    // 0..60
    #pragma unroll
    for (int i = 0; i < 64; i += 16) {
        int cp = tc + oc + i;
        int rowo = perm ? (32 * (cp >> 4) + (cp & 15) + guoff) : cp;
        ushort4 o;
        o.x = f2bf(tile[r4 + 0][oc + i]);
        o.y = f2bf(tile[r4 + 1][oc + i]);
        o.z = f2bf(tile[r4 + 2][oc + i]);
        o.w = f2bf(tile[r4 + 3][oc + i]);
        *(ushort4*)(dst + (size_t)rowo * R + tr + r4) = o;
    }
}

// ---------------- router: fp32 logits, softmax, top-2 -> cw[N][4]; also emits xb ----------------
__global__ void k_router(const float* __restrict__ x, const float* __restrict__ wr,
                         float* __restrict__ cw, unsigned short* __restrict__ xb) {
    int wv = threadIdx.x >> 6, lane = threadIdx.x & 63;
    int n = blockIdx.x * 4 + wv;
    const float* xr = x + (size_t)n * C_DIM;
    unsigned short* xbr = xb + (size_t)n * C_DIM;
    const float4* wr4 = (const float4*)wr;
    float p0 = 0.f, p1 = 0.f, p2 = 0.f, p3 = 0.f;
    for (int j = 0; j < C_DIM / 64; ++j) {
        int c = j * 64 + lane;
        float xv = xr[c];
        xbr[c] = f2bf(xv);
        float4 w = wr4[c];
        p0 += xv * w.x; p1 += xv * w.y; p2 += xv * w.z; p3 += xv * w.w;
    }
    #pragma unroll
    for (int off = 32; off > 0; off >>= 1) {
        p0 += __shfl_down(p0, off);
        p1 += __shfl_down(p1, off);
        p2 += __shfl_down(p2, off);
        p3 += __shfl_down(p3, off);
    }
    if (lane == 0) {
        float l[NE] = {p0, p1, p2, p3};
        float mx = fmaxf(fmaxf(l[0], l[1]), fmaxf(l[2], l[3]));
        float e0[NE]; float s = 0.f;
        #pragma unroll
        for (int i = 0; i < NE; ++i) { e0[i] = expf(l[i] - mx); s += e0[i]; }
        #pragma unroll
        for (int i = 0; i < NE; ++i) e0[i] /= s;
        int i1 = 0;
        #pragma unroll
        for (int i = 1; i < NE; ++i) if (e0[i] > e0[i1]) i1 = i;
        int i2 = -1;
        #pragma unroll
        for (int i = 0; i < NE; ++i) { if (i == i1) continue; if (i2 < 0 || e0[i] > e0[i2]) i2 = i; }
        float o[NE] = {0.f, 0.f, 0.f, 0.f};
        o[i1] = e0[i1]; o[i2] = e0[i2];
        *(float4*)(cw + (size_t)n * 4) = make_float4(o[0], o[1], o[2], o[3]);
    }
}

// ---------------- build per-expert token lists (deterministic, token-id order) ----------------
__global__ void k_build(const float* __restrict__ cw, int* __restrict__ rowlist,
                        float* __restrict__ cwg, int* __restrict__ pos2, int* __restrict__ meta) {
    __shared__ int lcnt[256][NE];
    int tid = threadIdx.x;
    int t0 = tid * 32;
    int c[NE] = {0, 0, 0, 0};
    for (int i = 0; i < 32; ++i) {
        const float* w = cw + (size_t)(t0 + i) * NE;
        #pragma unroll
        for (int e = 0; e < NE; ++e) if (w[e] > 0.f) c[e]++;
    }
    #pragma unroll
    for (int e = 0; e < NE; ++e) lcnt[tid][e] = c[e];
    __syncthreads();
    if (tid == 0) {
        int tot[NE] = {0, 0, 0, 0};
        for (int i = 0; i < 256; ++i)
            #pragma unroll
            for (int e = 0; e < NE; ++e) { int v = lcnt[i][e]; lcnt[i][e] = tot[e]; tot[e] += v; }
        int off = 0;
        #pragma unroll
        for (int e = 0; e < NE; ++e) {
            meta[e] = tot[e];
            int p = (tot[e] + 255) & ~255;
            meta[4 + e] = p;
            meta[8 + e] = off;
            off += p;
        }
        meta[12] = off;
    }
    __syncthreads();
    int pos[NE];
    #pragma unroll
    for (int e = 0; e < NE; ++e) pos[e] = lcnt[tid][e];
    for (int i = 0; i < 32; ++i) {
        int t = t0 + i;
        const float* w = cw + (size_t)t * NE;
        int sl = 0;
        #pragma unroll
        for (int e = 0; e < NE; ++e) if (w[e] > 0.f) {
            int p = meta[8 + e] + pos[e]++;
            rowlist[p] = t;
            cwg[p] = w[e];
            pos2[t * 2 + sl] = p;
            sl++;
        }
    }
    __syncthreads();
    if (tid < NE) {
        int e = tid;
        for (int p = meta[e]; p < meta[4 + e]; ++p) {
            rowlist[meta[8 + e] + p] = 0;
            cwg[meta[8 + e] + p] = 0.f;
        }
    }
}

// ================= 8-phase pipelined 256x256x64 GEMM core (full-hoist) =================
// 8 waves 2Mx4N, 8 rotating 16 KB unit slots, coalesced staging (R6) + conflict-
// free read swizzle (R7). NEW (R8): ZERO phase-start ds_reads -- every read is
// inside an MFMA window (uniform 4/8 read alternation, LDS pipe 576 cyc/phase
// under the 621-cyc MFMA cover). Enabled by a re-derived counted-vmcnt schedule:
// WAITV(6)@ph2, WAITV(4)@ph4, WAITV(6)@ph6, WAITV(4)@ph7 (each waits only for
// loads >=3 phases old -> free). Publish audit (steady state, slots in flight
// {4,5} at ph0): ph2 confirms 4,5 (read ph3-window); ph4 confirms 6,7,0 (reads
// ph5/ph7); ph6 confirms 1 (read ph7); ph7 confirms 2,3 (reads ph1-next). Every
// confirm precedes its read by >=1 barrier; every restage >=1 barrier after the
// slot's last read. Bit-identical data to R7.
#define SLOT_E 8192   // elems per unit slot

#define STAGE_U(P0, P1, slot, kofs) do { \
    gload_lds16((P0) + (kofs), smem + (slot) * SLOT_E + dc0); \
    gload_lds16((P1) + (kofs), smem + (slot) * SLOT_E + dc1); } while (0)
#define STG_A(slot, kofs) STAGE_U(aptr0, aptr1, slot, kofs)
#define STG_B(slot, kofs) STAGE_U(bptr0, bptr1, slot, kofs)

#define LDAL(bk, s) do { _Pragma("unroll") \
    for (int m_ = 0; m_ < 4; ++m_) af[bk][m_] = *(const bf16x8*)&smem[(s) * SLOT_E + rdA + m_ * 512]; } while (0)
#define LDAH(bk, s) do { _Pragma("unroll") \
    for (int m_ = 0; m_ < 4; ++m_) af[bk][m_] = *(const bf16x8*)&smem[(s) * SLOT_E + rdA + (4 + m_) * 512]; } while (0)
#define LDB_(bk, s) do { _Pragma("unroll") \
    for (int n_ = 0; n_ < 4; ++n_) bv[bk][n_] = *(const bf16x8*)&smem[(s) * SLOT_E + rdB + n_ * 512]; } while (0)

#define MMLO(ab, bb) do { _Pragma("unroll") \
    for (int m_ = 0; m_ < 4; ++m_) \
        _Pragma("unroll") \
        for (int n_ = 0; n_ < 4; ++n_) \
            acc[m_][n_] = __builtin_amdgcn_mfma_f32_16x16x32_bf16(af[ab][m_], bv[bb][n_], acc[m_][n_], 0, 0, 0); } while (0)
#define MMHI(ab, bb) do { _Pragma("unroll") \
    for (int m_ = 0; m_ < 4; ++m_) \
        _Pragma("unroll") \
        for (int n_ = 0; n_ < 4; ++n_) \
            acc[4 + m_][n_] = __builtin_amdgcn_mfma_f32_16x16x32_bf16(af[ab][m_], bv[bb][n_], acc[4 + m_][n_], 0, 0, 0); } while (0)

// Steady-state iteration: all reads inside MFMA windows; ph7 pre-reads next ph0.
#define ITER8H(kb) do { \
    /* ph0 */ STG_A(6, (kb) + 96);  BAR(); WAITL0();           PRIO1(); LDAH(1, 0);              MMLO(0, 0); PRIO0(); BAR(); \
    /* ph1 */ STG_B(7, (kb) + 96);  BAR(); WAITL0();           PRIO1(); LDAL(0, 2); LDB_(1, 3);  MMHI(1, 0); PRIO0(); BAR(); \
    /* ph2 */ STG_A(0, (kb) + 128); BAR(); WAITL0(); WAITV(6); PRIO1(); LDAH(1, 2);              MMLO(0, 1); PRIO0(); BAR(); \
    /* ph3 */ STG_B(1, (kb) + 128); BAR(); WAITL0();           PRIO1(); LDAL(0, 4); LDB_(0, 5);  MMHI(1, 1); PRIO0(); BAR(); \
    /* ph4 */ STG_A(2, (kb) + 160); BAR(); WAITL0(); WAITV(4); PRIO1(); LDAH(1, 4);              MMLO(0, 0); PRIO0(); BAR(); \
    /* ph5 */ STG_B(3, (kb) + 160); BAR(); WAITL0();           PRIO1(); LDAL(0, 6); LDB_(1, 7);  MMHI(1, 0); PRIO0(); BAR(); \
    /* ph6 */ STG_A(4, (kb) + 192); BAR(); WAITL0(); WAITV(6); PRIO1(); LDAH(1, 6);              MMLO(0, 1); PRIO0(); BAR(); \
    /* ph7 */ STG_B(5, (kb) + 192); BAR(); WAITL0(); WAITV(4); PRIO1(); LDAL(0, 0); LDB_(0, 1);  MMHI(1, 1); PRIO0(); BAR(); \
} while (0)

// Last iteration: only kb+96 half-tile staged; waits adjusted (no later stages);
// no next-iteration pre-read at ph7.
#define ITER8H_LAST(kb) do { \
    STG_A(6, (kb) + 96); BAR(); WAITL0();           PRIO1(); LDAH(1, 0);              MMLO(0, 0); PRIO0(); BAR(); \
    STG_B(7, (kb) + 96); BAR(); WAITL0();           PRIO1(); LDAL(0, 2); LDB_(1, 3);  MMHI(1, 0); PRIO0(); BAR(); \
                         BAR(); WAITL0(); WAITV(4); PRIO1(); LDAH(1, 2);              MMLO(0, 1); PRIO0(); BAR(); \
                         BAR(); WAITL0();           PRIO1(); LDAL(0, 4); LDB_(0, 5);  MMHI(1, 1); PRIO0(); BAR(); \
                         BAR(); WAITL0(); WAITV(0); PRIO1(); LDAH(1, 4);              MMLO(0, 0); PRIO0(); BAR(); \
                         BAR(); WAITL0();           PRIO1(); LDAL(0, 6); LDB_(1, 7);  MMHI(1, 0); PRIO0(); BAR(); \
                         BAR(); WAITL0();           PRIO1(); LDAH(1, 6);              MMLO(0, 1); PRIO0(); BAR(); \
                         BAR(); WAITL0();           PRIO1();                          MMHI(1, 1); PRIO0(); BAR(); \
} while (0)

// ---------------- merged gate+up GEMM (gathered A rows), silu epilogue ----------------
__global__ __launch_bounds__(512, 1) void k_gateup(
    const unsigned short* __restrict__ xb,
    const unsigned short* __restrict__ wgut,
    const int* __restrict__ rowlist,
    const int* __restrict__ meta,
    unsigned short* __restrict__ h,
    int cbase)
{
    extern __shared__ unsigned short smem[];
    int2 sb = strip_swz32();
    const int bx = sb.x, by = sb.y;
    const int p0 = cbase + by * 256;
    if (p0 >= meta[12]) return;
    const int e = (p0 >= meta[9]) + (p0 >= meta[10]) + (p0 >= meta[11]);

    const int tid = threadIdx.x;
    const int wid = tid >> 6, lane = tid & 63;
    const int wm = wid >> 2, wn = wid & 3;
    const int lrow = lane & 15, lkq = lane >> 4;

    // coalesced staging: inst j of wave wid covers rows 32*wid+16*j..+15;
    // lane l -> row +(l>>2), chunk (l&3)^((l>>3)&3) (quad = one 64B line).
    const int lsub = lane >> 2;                        // 0..15
    const int kc = ((lane & 3) ^ ((lane >> 3) & 3)) * 8;
    const int row0 = 32 * wid + lsub;
    const int dc0 = wid * 1024, dc1 = dc0 + 512;       // linear dest (unchanged)

    const unsigned short* aptr0 = xb + (size_t)rowlist[p0 + row0] * C_DIM + kc;
    const unsigned short* aptr1 = xb + (size_t)rowlist[p0 + row0 + 16] * C_DIM + kc;
    const unsigned short* Bb = wgut + (size_t)e * (2 * C_DIM * FF_DIM) + (size_t)(bx * 256) * C_DIM;
    const unsigned short* bptr0 = Bb + (size_t)row0 * C_DIM + kc;
    const unsigned short* bptr1 = Bb + (size_t)(row0 + 16) * C_DIM + kc;

    // read side: granule (row>>4)*512 elems; q = 4*lrow + (lkq ^ ((lrow>>1)&3))
    const int q8 = (4 * lrow + (lkq ^ ((lrow >> 1) & 3))) * 8;
    const int rdA = wm * 4096 + q8;    // granule base wm*8 * 512
    const int rdB = wn * 2048 + q8;    // granule base wn*4 * 512

    f32x4 acc[8][4] = {};
    bf16x8 af[2][4], bv[2][4];

    STG_A(0, 0);
    STG_B(1, 0);
    STG_A(2, 32);
    STG_B(3, 32);
    STG_A(4, 64);
    STG_B(5, 64);
    WAITV(4);          // confirms slots 0,1,2,3; leaves {4,5} in flight
    BAR();
    LDAL(0, 0);        // prologue pre-read for ph0 (replaces hoisted "ph7-prev")
    LDB_(0, 1);

    const int NI = C_DIM / 128;            // 8
    #pragma unroll 1
    for (int i = 0; i < NI - 1; ++i) {
        const int kb = 128 * i;
        ITER8H(kb);
    }
    ITER8H_LAST(128 * (NI - 1));

    // epilogue: h = silu(gate) * up ; ni pairs (2j,2j+1) -> ff = bx*128 + wn*32 + 16j + lrow
    const int ffb = bx * 128 + wn * 32;
    #pragma unroll
    for (int mi = 0; mi < 8; ++mi) {
        int row = by * 256 + wm * 128 + mi * 16 + lkq * 4;   // chunk-relative h row
        #pragma unroll
        for (int j = 0; j < 2; ++j) {
            int ff = ffb + 16 * j + lrow;
            f32x4 g = acc[mi][2 * j];
            f32x4 u = acc[mi][2 * j + 1];
            #pragma unroll
            for (int r = 0; r < 4; ++r) {
                float gv = g[r];
                float hv = gv / (1.f + __expf(-gv)) * u[r];
                h[(size_t)(row + r) * FF_DIM + ff] = f2bf(hv);
            }
        }
    }
}

// ---------------- down GEMM, same core: yd[p] = cwg[p] * (h @ wd[e]) ----------------
__global__ __launch_bounds__(512, 1) void k_down(
    const unsigned short* __restrict__ h,
    const unsigned short* __restrict__ wdt,
    const float* __restrict__ cwg,
    const int* __restrict__ meta,
    unsigned short* __restrict__ yd,
    int cbase)
{
    extern __shared__ unsigned short smem[];
    int2 sb = xcd_swz(gridDim.x, gridDim.y);
    const int bx = sb.x, by = sb.y;
    const int p0 = cbase + by * 256;
    if (p0 >= meta[12]) return;
    const int e = (p0 >= meta[9]) + (p0 >= meta[10]) + (p0 >= meta[11]);

    const int tid = threadIdx.x;
    const int wid = tid >> 6, lane = tid & 63;
    const int wm = wid >> 2, wn = wid & 3;
    const int lrow = lane & 15, lkq = lane >> 4;

    const int lsub = lane >> 2;
    const int kc = ((lane & 3) ^ ((lane >> 3) & 3)) * 8;
    const int row0 = 32 * wid + lsub;
    const int dc0 = wid * 1024, dc1 = dc0 + 512;

    const unsigned short* Ab = h + (size_t)(by * 256) * FF_DIM;   // chunk-relative packed rows
    const unsigned short* aptr0 = Ab + (size_t)row0 * FF_DIM + kc;
    const unsigned short* aptr1 = Ab + (size_t)(row0 + 16) * FF_DIM + kc;
    const unsigned short* Bb = wdt + (size_t)e * (C_DIM * FF_DIM) + (size_t)(bx * 256) * FF_DIM;
    const unsigned short* bptr0 = Bb + (size_t)row0 * FF_DIM + kc;
    const unsigned short* bptr1 = Bb + (size_t)(row0 + 16) * FF_DIM + kc;

    const int q8 = (4 * lrow + (lkq ^ ((lrow >> 1) & 3))) * 8;
    const int rdA = wm * 4096 + q8;
    const int rdB = wn * 2048 + q8;

    f32x4 acc[8][4] = {};
    bf16x8 af[2][4], bv[2][4];

    STG_A(0, 0);
    STG_B(1, 0);
    STG_A(2, 32);
    STG_B(3, 32);
    STG_A(4, 64);
    STG_B(5, 64);
    WAITV(4);
    BAR();
    LDAL(0, 0);
    LDB_(0, 1);

    const int NI = FF_DIM / 128;           // 32
    #pragma unroll 1
    for (int i = 0; i < NI - 1; ++i) {
        const int kb = 128 * i;
        ITER8H(kb);
    }
    ITER8H_LAST(128 * (NI - 1));

    // epilogue: yd[p][col] = cwg[p] * acc (pads have cwg=0; rows unread)
    #pragma unroll
    for (int mi = 0; mi < 8; ++mi) {
        int pb = p0 + wm * 128 + mi * 16 + lkq * 4;
        float w4[4];
        #pragma unroll
        for (int r = 0; r < 4; ++r) w4[r] = cwg[pb + r];
        #pragma unroll
        for (int ni = 0; ni < 4; ++ni) {
            int col = bx * 256 + wn * 64 + ni * 16 + lrow;
            f32x4 a = acc[mi][ni];
            #pragma unroll
            for (int r = 0; r < 4; ++r)
                yd[(size_t)(pb + r) * C_DIM + col] = f2bf(w4[r] * a[r]);
        }
    }
}

// ---------------- combine: out[t] = yd[slotA] + yd[slotB] (deterministic) ----------------
__global__ void k_combine(const unsigned short* __restrict__ yd, const int* __restrict__ pos2,
                          float* __restrict__ out) {
    int t = blockIdx.x;
    int c4 = threadIdx.x * 4;
    int pA = pos2[t * 2], pB = pos2[t * 2 + 1];
    ushort4 a = *(const ushort4*)(yd + (size_t)pA * C_DIM + c4);
    ushort4 b = *(const ushort4*)(yd + (size_t)pB * C_DIM + c4);
    float4 o;
    o.x = bf2f(a.x) + bf2f(b.x);
    o.y = bf2f(a.y) + bf2f(b.y);
    o.z = bf2f(a.z) + bf2f(b.z);
    o.w = bf2f(a.w) + bf2f(b.w);
    *(float4*)(out + (size_t)t * C_DIM + c4) = o;
}

extern "C" void kernel_launch(void* const* d_in, const int* in_sizes, int n_in,
                              void* d_out, int out_size, void* d_ws, size_t ws_size,
                              hipStream_t stream) {
    (void)in_sizes; (void)n_in; (void)out_size;
    const float* x   = (const float*)d_in[0];
    const float* w_r = (const float*)d_in[1];
    const float* w_g = (const float*)d_in[2];
    const float* w_u = (const float*)d_in[3];
    const float* w_d = (const float*)d_in[4];
    float* out = (float*)d_out;

    char* ws = (char*)d_ws;
    unsigned short* xb   = (unsigned short*)(ws);                    // 16,777,216
    unsigned short* wgut = (unsigned short*)(ws + 16777216);         // 67,108,864
    unsigned short* wdt  = (unsigned short*)(ws + 83886080);         // 33,554,432
    unsigned short* yd   = (unsigned short*)(ws + 117440512);        // 35,651,584 (17408 x 1024)
    float*          cw   = (float*)(ws + 153092096);                 //    131,072
    int*            rowlist = (int*)(ws + 153223168);                //     69,632
    float*          cwg  = (float*)(ws + 153292800);                 //     69,632
    int*            pos2 = (int*)(ws + 153362432);                   //     65,536
    int*            meta = (int*)(ws + 153427968);                   //        512
    unsigned short* h    = (unsigned short*)(ws + 153428480);        // chunked: 2 MiB / 256-row block

    hipFuncSetAttribute((const void*)k_gateup, hipFuncAttributeMaxDynamicSharedMemorySize, 8 * SLOT_E * 2);
    hipFuncSetAttribute((const void*)k_down,   hipFuncAttributeMaxDynamicSharedMemorySize, 8 * SLOT_E * 2);

    size_t h_avail = ws_size > 153428480 ? ws_size - 153428480 : 0;
    int maxb = (int)(h_avail / (256 * FF_DIM * 2));   // 2 MiB per 256-row block
    if (maxb < 1) maxb = 1;
    if (maxb > TOTB256) maxb = TOTB256;
    int nch = (TOTB256 + maxb - 1) / maxb;

    k_router<<<N_TOK / 4, 256, 0, stream>>>(x, w_r, cw, xb);
    k_build<<<1, 256, 0, stream>>>(cw, rowlist, cwg, pos2, meta);

    k_tconv<<<dim3(FF_DIM / 64, C_DIM / 64, NE), 256, 0, stream>>>(w_g, wgut, C_DIM, FF_DIM, (size_t)2 * C_DIM * FF_DIM, 1, 0);
    k_tconv<<<dim3(FF_DIM / 64, C_DIM / 64, NE), 256, 0, stream>>>(w_u, wgut, C_DIM, FF_DIM, (size_t)2 * C_DIM * FF_DIM, 1, 16);
    k_tconv<<<dim3(C_DIM / 64, FF_DIM / 64, NE), 256, 0, stream>>>(w_d, wdt, FF_DIM, C_DIM, (size_t)C_DIM * FF_DIM, 0, 0);

    for (int c = 0; c < nch; ++c) {
        int cb = c * maxb;
        int nb = (TOTB256 - cb) < maxb ? (TOTB256 - cb) : maxb;
        k_gateup<<<dim3(2 * FF_DIM / 256, nb), 512, 8 * SLOT_E * 2, stream>>>(xb, wgut, rowlist, meta, h, cb * 256);
        k_down<<<dim3(C_DIM / 256, nb), 512, 8 * SLOT_E * 2, stream>>>(h, wdt, cwg, meta, yd, cb * 256);
    }
    k_combine<<<N_TOK, 256, 0, stream>>>(yd, pos2, out);
}

// Round 9
// 624.308 us; speedup vs baseline: 5.3031x; 1.0231x over previous
//
#include <hip/hip_runtime.h>
#include <hip/hip_bf16.h>

#define N_TOK 8192
#define C_DIM 1024
#define FF_DIM 4096
#define NE 4
#define ROWS_MAX 17408           // max padded packed rows (16384 + 4*256 slack)
#define TOTB256 68               // ROWS_MAX / 256

typedef __attribute__((ext_vector_type(8))) short bf16x8;
typedef __attribute__((ext_vector_type(4))) float f32x4;

__device__ __forceinline__ unsigned short f2bf(float f) {
    union { float f; unsigned int u; } v; v.f = f;
    return (unsigned short)((v.u + 0x7FFFu + ((v.u >> 16) & 1u)) >> 16);
}
__device__ __forceinline__ float bf2f(unsigned short u) {
    union { unsigned int u; float f; } v; v.u = ((unsigned int)u) << 16;
    return v.f;
}

__device__ __forceinline__ void gload_lds16(const void* g, void* l) {
    __builtin_amdgcn_global_load_lds(
        (const __attribute__((address_space(1))) unsigned int*)g,
        (__attribute__((address_space(3))) unsigned int*)l, 16, 0, 0);
}

#define WAITV(N) do { asm volatile("s_waitcnt vmcnt(" #N ")" ::: "memory"); __builtin_amdgcn_sched_barrier(0); } while (0)
#define WAITL0()  do { asm volatile("s_waitcnt lgkmcnt(0)" ::: "memory"); __builtin_amdgcn_sched_barrier(0); } while (0)
#define BAR()     do { __builtin_amdgcn_s_barrier(); __builtin_amdgcn_sched_barrier(0); } while (0)
#define PRIO1()   __builtin_amdgcn_s_setprio(1)
#define PRIO0()   __builtin_amdgcn_s_setprio(0)

// bijective XCD-aware block swizzle (m204): contiguous id-chunks per XCD (k_down)
__device__ __forceinline__ int2 xcd_swz(int gx, int gy) {
    int wg = blockIdx.y * gx + blockIdx.x;
    int nwg = gx * gy;
    int q = nwg >> 3, r = nwg & 7;
    int xcd = wg & 7, idx = wg >> 3;
    int swz = (xcd < r) ? (xcd * (q + 1) + idx) : (r * (q + 1) + (xcd - r) * q + idx);
    return make_int2(swz % gx, swz / gx);
}

// gateup strip swizzle (gx==32 only): each XCD owns a 4-bx column strip; its 32
// concurrent blocks form 4bx x 8by -> B working set L2-resident.
__device__ __forceinline__ int2 strip_swz32() {
    int wg = blockIdx.y * 32 + blockIdx.x;
    int xcd = wg & 7, idx = wg >> 3;
    int bx = xcd * 4 + (idx & 3);
    int by = (idx >> 4) * 4 + ((idx >> 2) & 3);
    return make_int2(bx, by);
}

// ------- transpose+convert: src fp32 [z][R][S] -> dst bf16 [z][S][R]
__global__ void k_tconv(const float* __restrict__ src0, unsigned short* __restrict__ dst0,
                        int R, int S, size_t dz, int perm, int guoff) {
    __shared__ float tile[64][65];
    const float* src = src0 + (size_t)blockIdx.z * R * S;
    unsigned short* dst = dst0 + (size_t)blockIdx.z * dz;
    const int tc = blockIdx.x * 64;
    const int tr = blockIdx.y * 64;
    const int tid = threadIdx.x;
    const int lr = tid >> 4;          // 0..15
    const int lc4 = (tid & 15) * 4;   // 0..60
    #pragma unroll
    for (int i = 0; i < 64; i += 16) {
        float4 v = *(const float4*)(src + (size_t)(tr + lr + i) * S + tc + lc4);
        tile[lr + i][lc4 + 0] = v.x;
        tile[lr + i][lc4 + 1] = v.y;
        tile[lr + i][lc4 + 2] = v.z;
        tile[lr + i][lc4 + 3] = v.w;
    }
    __syncthreads();
    const int oc = tid >> 4;          // 0..15
    const int r4 = (tid & 15) * 4;    // 0..60
    #pragma unroll
    for (int i = 0; i < 64; i += 16) {
        int cp = tc + oc + i;
        int rowo = perm ? (32 * (cp >> 4) + (cp & 15) + guoff) : cp;
        ushort4 o;
        o.x = f2bf(tile[r4 + 0][oc + i]);
        o.y = f2bf(tile[r4 + 1][oc + i]);
        o.z = f2bf(tile[r4 + 2][oc + i]);
        o.w = f2bf(tile[r4 + 3][oc + i]);
        *(ushort4*)(dst + (size_t)rowo * R + tr + r4) = o;
    }
}

// ---------------- router: fp32 logits, softmax, top-2 -> cw[N][4]; also emits xb ----------------
__global__ void k_router(const float* __restrict__ x, const float* __restrict__ wr,
                         float* __restrict__ cw, unsigned short* __restrict__ xb) {
    int wv = threadIdx.x >> 6, lane = threadIdx.x & 63;
    int n = blockIdx.x * 4 + wv;
    const float* xr = x + (size_t)n * C_DIM;
    unsigned short* xbr = xb + (size_t)n * C_DIM;
    const float4* wr4 = (const float4*)wr;
    float p0 = 0.f, p1 = 0.f, p2 = 0.f, p3 = 0.f;
    for (int j = 0; j < C_DIM / 64; ++j) {
        int c = j * 64 + lane;
        float xv = xr[c];
        xbr[c] = f2bf(xv);
        float4 w = wr4[c];
        p0 += xv * w.x; p1 += xv * w.y; p2 += xv * w.z; p3 += xv * w.w;
    }
    #pragma unroll
    for (int off = 32; off > 0; off >>= 1) {
        p0 += __shfl_down(p0, off);
        p1 += __shfl_down(p1, off);
        p2 += __shfl_down(p2, off);
        p3 += __shfl_down(p3, off);
    }
    if (lane == 0) {
        float l[NE] = {p0, p1, p2, p3};
        float mx = fmaxf(fmaxf(l[0], l[1]), fmaxf(l[2], l[3]));
        float e0[NE]; float s = 0.f;
        #pragma unroll
        for (int i = 0; i < NE; ++i) { e0[i] = expf(l[i] - mx); s += e0[i]; }
        #pragma unroll
        for (int i = 0; i < NE; ++i) e0[i] /= s;
        int i1 = 0;
        #pragma unroll
        for (int i = 1; i < NE; ++i) if (e0[i] > e0[i1]) i1 = i;
        int i2 = -1;
        #pragma unroll
        for (int i = 0; i < NE; ++i) { if (i == i1) continue; if (i2 < 0 || e0[i] > e0[i2]) i2 = i; }
        float o[NE] = {0.f, 0.f, 0.f, 0.f};
        o[i1] = e0[i1]; o[i2] = e0[i2];
        *(float4*)(cw + (size_t)n * 4) = make_float4(o[0], o[1], o[2], o[3]);
    }
}

// ---------------- build per-expert token lists (deterministic, token-id order) ----------------
__global__ void k_build(const float* __restrict__ cw, int* __restrict__ rowlist,
                        float* __restrict__ cwg, int* __restrict__ pos2, int* __restrict__ meta) {
    __shared__ int lcnt[256][NE];
    int tid = threadIdx.x;
    int t0 = tid * 32;
    int c[NE] = {0, 0, 0, 0};
    for (int i = 0; i < 32; ++i) {
        const float* w = cw + (size_t)(t0 + i) * NE;
        #pragma unroll
        for (int e = 0; e < NE; ++e) if (w[e] > 0.f) c[e]++;
    }
    #pragma unroll
    for (int e = 0; e < NE; ++e) lcnt[tid][e] = c[e];
    __syncthreads();
    if (tid == 0) {
        int tot[NE] = {0, 0, 0, 0};
        for (int i = 0; i < 256; ++i)
            #pragma unroll
            for (int e = 0; e < NE; ++e) { int v = lcnt[i][e]; lcnt[i][e] = tot[e]; tot[e] += v; }
        int off = 0;
        #pragma unroll
        for (int e = 0; e < NE; ++e) {
            meta[e] = tot[e];
            int p = (tot[e] + 255) & ~255;
            meta[4 + e] = p;
            meta[8 + e] = off;
            off += p;
        }
        meta[12] = off;
    }
    __syncthreads();
    int pos[NE];
    #pragma unroll
    for (int e = 0; e < NE; ++e) pos[e] = lcnt[tid][e];
    for (int i = 0; i < 32; ++i) {
        int t = t0 + i;
        const float* w = cw + (size_t)t * NE;
        int sl = 0;
        #pragma unroll
        for (int e = 0; e < NE; ++e) if (w[e] > 0.f) {
            int p = meta[8 + e] + pos[e]++;
            rowlist[p] = t;
            cwg[p] = w[e];
            pos2[t * 2 + sl] = p;
            sl++;
        }
    }
    __syncthreads();
    if (tid < NE) {
        int e = tid;
        for (int p = meta[e]; p < meta[4 + e]; ++p) {
            rowlist[meta[8 + e] + p] = 0;
            cwg[meta[8 + e] + p] = 0.f;
        }
    }
}

// ================= gateup core: 8-phase full-hoist 256x256 (R8, unchanged) =================
#define SLOT_E 8192   // elems per unit slot

#define STAGE_U(P0, P1, slot, kofs) do { \
    gload_lds16((P0) + (kofs), smem + (slot) * SLOT_E + dc0); \
    gload_lds16((P1) + (kofs), smem + (slot) * SLOT_E + dc1); } while (0)
#define STG_A(slot, kofs) STAGE_U(aptr0, aptr1, slot, kofs)
#define STG_B(slot, kofs) STAGE_U(bptr0, bptr1, slot, kofs)

#define LDAL(bk, s) do { _Pragma("unroll") \
    for (int m_ = 0; m_ < 4; ++m_) af[bk][m_] = *(const bf16x8*)&smem[(s) * SLOT_E + rdA + m_ * 512]; } while (0)
#define LDAH(bk, s) do { _Pragma("unroll") \
    for (int m_ = 0; m_ < 4; ++m_) af[bk][m_] = *(const bf16x8*)&smem[(s) * SLOT_E + rdA + (4 + m_) * 512]; } while (0)
#define LDB_(bk, s) do { _Pragma("unroll") \
    for (int n_ = 0; n_ < 4; ++n_) bv[bk][n_] = *(const bf16x8*)&smem[(s) * SLOT_E + rdB + n_ * 512]; } while (0)

#define MMLO(ab, bb) do { _Pragma("unroll") \
    for (int m_ = 0; m_ < 4; ++m_) \
        _Pragma("unroll") \
        for (int n_ = 0; n_ < 4; ++n_) \
            acc[m_][n_] = __builtin_amdgcn_mfma_f32_16x16x32_bf16(af[ab][m_], bv[bb][n_], acc[m_][n_], 0, 0, 0); } while (0)
#define MMHI(ab, bb) do { _Pragma("unroll") \
    for (int m_ = 0; m_ < 4; ++m_) \
        _Pragma("unroll") \
        for (int n_ = 0; n_ < 4; ++n_) \
            acc[4 + m_][n_] = __builtin_amdgcn_mfma_f32_16x16x32_bf16(af[ab][m_], bv[bb][n_], acc[4 + m_][n_], 0, 0, 0); } while (0)

#define ITER8H(kb) do { \
    /* ph0 */ STG_A(6, (kb) + 96);  BAR(); WAITL0();           PRIO1(); LDAH(1, 0);              MMLO(0, 0); PRIO0(); BAR(); \
    /* ph1 */ STG_B(7, (kb) + 96);  BAR(); WAITL0();           PRIO1(); LDAL(0, 2); LDB_(1, 3);  MMHI(1, 0); PRIO0(); BAR(); \
    /* ph2 */ STG_A(0, (kb) + 128); BAR(); WAITL0(); WAITV(6); PRIO1(); LDAH(1, 2);              MMLO(0, 1); PRIO0(); BAR(); \
    /* ph3 */ STG_B(1, (kb) + 128); BAR(); WAITL0();           PRIO1(); LDAL(0, 4); LDB_(0, 5);  MMHI(1, 1); PRIO0(); BAR(); \
    /* ph4 */ STG_A(2, (kb) + 160); BAR(); WAITL0(); WAITV(4); PRIO1(); LDAH(1, 4);              MMLO(0, 0); PRIO0(); BAR(); \
    /* ph5 */ STG_B(3, (kb) + 160); BAR(); WAITL0();           PRIO1(); LDAL(0, 6); LDB_(1, 7);  MMHI(1, 0); PRIO0(); BAR(); \
    /* ph6 */ STG_A(4, (kb) + 192); BAR(); WAITL0(); WAITV(6); PRIO1(); LDAH(1, 6);              MMLO(0, 1); PRIO0(); BAR(); \
    /* ph7 */ STG_B(5, (kb) + 192); BAR(); WAITL0(); WAITV(4); PRIO1(); LDAL(0, 0); LDB_(0, 1);  MMHI(1, 1); PRIO0(); BAR(); \
} while (0)

#define ITER8H_LAST(kb) do { \
    STG_A(6, (kb) + 96); BAR(); WAITL0();           PRIO1(); LDAH(1, 0);              MMLO(0, 0); PRIO0(); BAR(); \
    STG_B(7, (kb) + 96); BAR(); WAITL0();           PRIO1(); LDAL(0, 2); LDB_(1, 3);  MMHI(1, 0); PRIO0(); BAR(); \
                         BAR(); WAITL0(); WAITV(4); PRIO1(); LDAH(1, 2);              MMLO(0, 1); PRIO0(); BAR(); \
                         BAR(); WAITL0();           PRIO1(); LDAL(0, 4); LDB_(0, 5);  MMHI(1, 1); PRIO0(); BAR(); \
                         BAR(); WAITL0(); WAITV(0); PRIO1(); LDAH(1, 4);              MMLO(0, 0); PRIO0(); BAR(); \
                         BAR(); WAITL0();           PRIO1(); LDAL(0, 6); LDB_(1, 7);  MMHI(1, 0); PRIO0(); BAR(); \
                         BAR(); WAITL0();           PRIO1(); LDAH(1, 6);              MMLO(0, 1); PRIO0(); BAR(); \
                         BAR(); WAITL0();           PRIO1();                          MMHI(1, 1); PRIO0(); BAR(); \
} while (0)

// ---------------- merged gate+up GEMM (gathered A rows), silu epilogue ----------------
__global__ __launch_bounds__(512, 1) void k_gateup(
    const unsigned short* __restrict__ xb,
    const unsigned short* __restrict__ wgut,
    const int* __restrict__ rowlist,
    const int* __restrict__ meta,
    unsigned short* __restrict__ h,
    int cbase)
{
    extern __shared__ unsigned short smem[];
    int2 sb = strip_swz32();
    const int bx = sb.x, by = sb.y;
    const int p0 = cbase + by * 256;
    if (p0 >= meta[12]) return;
    const int e = (p0 >= meta[9]) + (p0 >= meta[10]) + (p0 >= meta[11]);

    const int tid = threadIdx.x;
    const int wid = tid >> 6, lane = tid & 63;
    const int wm = wid >> 2, wn = wid & 3;
    const int lrow = lane & 15, lkq = lane >> 4;

    const int lsub = lane >> 2;                        // 0..15
    const int kc = ((lane & 3) ^ ((lane >> 3) & 3)) * 8;
    const int row0 = 32 * wid + lsub;
    const int dc0 = wid * 1024, dc1 = dc0 + 512;       // linear dest

    const unsigned short* aptr0 = xb + (size_t)rowlist[p0 + row0] * C_DIM + kc;
    const unsigned short* aptr1 = xb + (size_t)rowlist[p0 + row0 + 16] * C_DIM + kc;
    const unsigned short* Bb = wgut + (size_t)e * (2 * C_DIM * FF_DIM) + (size_t)(bx * 256) * C_DIM;
    const unsigned short* bptr0 = Bb + (size_t)row0 * C_DIM + kc;
    const unsigned short* bptr1 = Bb + (size_t)(row0 + 16) * C_DIM + kc;

    const int q8 = (4 * lrow + (lkq ^ ((lrow >> 1) & 3))) * 8;
    const int rdA = wm * 4096 + q8;    // granule base wm*8 * 512
    const int rdB = wn * 2048 + q8;    // granule base wn*4 * 512

    f32x4 acc[8][4] = {};
    bf16x8 af[2][4], bv[2][4];

    STG_A(0, 0);
    STG_B(1, 0);
    STG_A(2, 32);
    STG_B(3, 32);
    STG_A(4, 64);
    STG_B(5, 64);
    WAITV(4);          // confirms slots 0..3; {4,5} in flight
    BAR();
    LDAL(0, 0);        // prologue pre-read for ph0
    LDB_(0, 1);

    const int NI = C_DIM / 128;            // 8
    #pragma unroll 1
    for (int i = 0; i < NI - 1; ++i) {
        const int kb = 128 * i;
        ITER8H(kb);
    }
    ITER8H_LAST(128 * (NI - 1));

    // epilogue: h = silu(gate) * up
    const int ffb = bx * 128 + wn * 32;
    #pragma unroll
    for (int mi = 0; mi < 8; ++mi) {
        int row = by * 256 + wm * 128 + mi * 16 + lkq * 4;   // chunk-relative h row
        #pragma unroll
        for (int j = 0; j < 2; ++j) {
            int ff = ffb + 16 * j + lrow;
            f32x4 g = acc[mi][2 * j];
            f32x4 u = acc[mi][2 * j + 1];
            #pragma unroll
            for (int r = 0; r < 4; ++r) {
                float gv = g[r];
                float hv = gv / (1.f + __expf(-gv)) * u[r];
                h[(size_t)(row + r) * FF_DIM + ff] = f2bf(hv);
            }
        }
    }
}

// ================= k_down core: 256x128 tile, 3 rotating pairs, 2 blocks/CU =================
// 8 waves as 4M x 2N, wave tile 64x64 (acc[4][4] = 64 VGPR; R5 proved no spill
// at this geometry). LDS pair = A[256x32] 16 KB + B[128x32] 8 KB = 24 KB; 3
// pairs = 72 KB -> 2 blocks/CU. Grid 8bx x 68by = 544 half-size blocks ->
// makespan ~1.06 work-rounds (vs 272 full blocks = 2.0 rounds: the tail was
// ~116 us of idle CUs). Phase-start ds_reads are covered by the co-resident
// block (TLP), which the 1-block lockstep core lacked. Staging/read mappings
// are the R6 coalesced + R7 conflict-free swizzle (granule layout identical).
// Counted WAITV(3): at phase t (stage of halftile t+2 issued, t+1 & t+2 in
// flight = 6 loads) waits to <=3 -> confirms t+1 one barrier before its read.
#define D_PAIR 12288   // elems per pair (A 8192 + B 4096)

#define D_STG(pn, KO) do { \
    gload_lds16(aptr0 + (KO), smem + (pn) * D_PAIR + dcA0); \
    gload_lds16(aptr1 + (KO), smem + (pn) * D_PAIR + dcA1); \
    gload_lds16(bptr0 + (KO), smem + (pn) * D_PAIR + 8192 + dcB); } while (0)

#define D_PH(p, STG, WV) do { \
    _Pragma("unroll") \
    for (int m_ = 0; m_ < 4; ++m_) af[m_] = *(const bf16x8*)&smem[(p) * D_PAIR + rdA + m_ * 512]; \
    _Pragma("unroll") \
    for (int n_ = 0; n_ < 4; ++n_) bv[n_] = *(const bf16x8*)&smem[(p) * D_PAIR + 8192 + rdB + n_ * 512]; \
    STG; \
    BAR(); \
    WAITL0(); \
    PRIO1(); \
    _Pragma("unroll") \
    for (int m_ = 0; m_ < 4; ++m_) \
        _Pragma("unroll") \
        for (int n_ = 0; n_ < 4; ++n_) \
            acc[m_][n_] = __builtin_amdgcn_mfma_f32_16x16x32_bf16(af[m_], bv[n_], acc[m_][n_], 0, 0, 0); \
    PRIO0(); \
    WV; \
    BAR(); \
} while (0)

__global__ __launch_bounds__(512, 4) void k_down(
    const unsigned short* __restrict__ h,
    const unsigned short* __restrict__ wdt,
    const float* __restrict__ cwg,
    const int* __restrict__ meta,
    unsigned short* __restrict__ yd,
    int cbase)
{
    extern __shared__ unsigned short smem[];
    int2 sb = xcd_swz(gridDim.x, gridDim.y);
    const int bx = sb.x, by = sb.y;
    const int p0 = cbase + by * 256;
    if (p0 >= meta[12]) return;
    const int e = (p0 >= meta[9]) + (p0 >= meta[10]) + (p0 >= meta[11]);

    const int tid = threadIdx.x;
    const int wid = tid >> 6, lane = tid & 63;
    const int wm = wid >> 1, wn = wid & 1;      // 4M x 2N, wave tile 64x64
    const int lrow = lane & 15, lkq = lane >> 4;

    // coalesced staging (R6 mapping): A inst j of wave wid covers rows
    // 32*wid+16*j..+15; B inst covers rows 16*wid..+15. lane l -> row +(l>>2),
    // chunk (l&3)^((l>>3)&3) (quad = one fully-consumed 64B line).
    const int lsub = lane >> 2;                        // 0..15
    const int kc = ((lane & 3) ^ ((lane >> 3) & 3)) * 8;
    const int rowA0 = 32 * wid + lsub;
    const int rowB0 = 16 * wid + lsub;
    const int dcA0 = wid * 1024, dcA1 = dcA0 + 512;
    const int dcB  = wid * 512;

    const unsigned short* Ab = h + (size_t)(by * 256) * FF_DIM;   // chunk-relative packed rows
    const unsigned short* aptr0 = Ab + (size_t)rowA0 * FF_DIM + kc;
    const unsigned short* aptr1 = Ab + (size_t)(rowA0 + 16) * FF_DIM + kc;
    const unsigned short* Bb = wdt + (size_t)e * (C_DIM * FF_DIM) + (size_t)(bx * 128) * FF_DIM;
    const unsigned short* bptr0 = Bb + (size_t)rowB0 * FF_DIM + kc;

    // read side (R7 conflict-free): q = 4*lrow + (lkq ^ ((lrow>>1)&3))
    const int q8 = (4 * lrow + (lkq ^ ((lrow >> 1) & 3))) * 8;
    const int rdA = wm * 2048 + q8;    // A granules wm*4 + mi
    const int rdB = wn * 2048 + q8;    // B granules wn*4 + ni

    f32x4 acc[4][4] = {};
    bf16x8 af[4], bv[4];

    // prologue: halftiles 0,1 into pairs 0,1
    D_STG(0, 0);
    D_STG(1, 32);
    WAITV(3);      // halftile 0 complete; halftile 1 in flight
    BAR();

    // 128 halftiles = 42 x 3 phases + 2 tail (phase t: read pair t%3, stage t+2)
    #pragma unroll 1
    for (int i = 0; i < 42; ++i) {
        const int ko = 96 * i;
        D_PH(0, D_STG(2, ko + 64),  WAITV(3));
        D_PH(1, D_STG(0, ko + 96),  WAITV(3));
        D_PH(2, D_STG(1, ko + 128), WAITV(3));
    }
    D_PH(0, (void)0, WAITV(0));    // halftile 126
    D_PH(1, (void)0, (void)0);     // halftile 127

    // epilogue: yd[p][col] = cwg[p] * acc (pads have cwg=0; rows unread)
    #pragma unroll
    for (int mi = 0; mi < 4; ++mi) {
        int pb = p0 + wm * 64 + mi * 16 + lkq * 4;
        float w4[4];
        #pragma unroll
        for (int r = 0; r < 4; ++r) w4[r] = cwg[pb + r];
        #pragma unroll
        for (int ni = 0; ni < 4; ++ni) {
            int col = bx * 128 + wn * 64 + ni * 16 + lrow;
            f32x4 a = acc[mi][ni];
            #pragma unroll
            for (int r = 0; r < 4; ++r)
                yd[(size_t)(pb + r) * C_DIM + col] = f2bf(w4[r] * a[r]);
        }
    }
}

// ---------------- combine: out[t] = yd[slotA] + yd[slotB] (deterministic) ----------------
__global__ void k_combine(const unsigned short* __restrict__ yd, const int* __restrict__ pos2,
                          float* __restrict__ out) {
    int t = blockIdx.x;
    int c4 = threadIdx.x * 4;
    int pA = pos2[t * 2], pB = pos2[t * 2 + 1];
    ushort4 a = *(const ushort4*)(yd + (size_t)pA * C_DIM + c4);
    ushort4 b = *(const ushort4*)(yd + (size_t)pB * C_DIM + c4);
    float4 o;
    o.x = bf2f(a.x) + bf2f(b.x);
    o.y = bf2f(a.y) + bf2f(b.y);
    o.z = bf2f(a.z) + bf2f(b.z);
    o.w = bf2f(a.w) + bf2f(b.w);
    *(float4*)(out + (size_t)t * C_DIM + c4) = o;
}

extern "C" void kernel_launch(void* const* d_in, const int* in_sizes, int n_in,
                              void* d_out, int out_size, void* d_ws, size_t ws_size,
                              hipStream_t stream) {
    (void)in_sizes; (void)n_in; (void)out_size;
    const float* x   = (const float*)d_in[0];
    const float* w_r = (const float*)d_in[1];
    const float* w_g = (const float*)d_in[2];
    const float* w_u = (const float*)d_in[3];
    const float* w_d = (const float*)d_in[4];
    float* out = (float*)d_out;

    char* ws = (char*)d_ws;
    unsigned short* xb   = (unsigned short*)(ws);                    // 16,777,216
    unsigned short* wgut = (unsigned short*)(ws + 16777216);         // 67,108,864
    unsigned short* wdt  = (unsigned short*)(ws + 83886080);         // 33,554,432
    unsigned short* yd   = (unsigned short*)(ws + 117440512);        // 35,651,584 (17408 x 1024)
    float*          cw   = (float*)(ws + 153092096);                 //    131,072
    int*            rowlist = (int*)(ws + 153223168);                //     69,632
    float*          cwg  = (float*)(ws + 153292800);                 //     69,632
    int*            pos2 = (int*)(ws + 153362432);                   //     65,536
    int*            meta = (int*)(ws + 153427968);                   //        512
    unsigned short* h    = (unsigned short*)(ws + 153428480);        // chunked: 2 MiB / 256-row block

    hipFuncSetAttribute((const void*)k_gateup, hipFuncAttributeMaxDynamicSharedMemorySize, 8 * SLOT_E * 2);
    hipFuncSetAttribute((const void*)k_down,   hipFuncAttributeMaxDynamicSharedMemorySize, 3 * D_PAIR * 2);

    size_t h_avail = ws_size > 153428480 ? ws_size - 153428480 : 0;
    int maxb = (int)(h_avail / (256 * FF_DIM * 2));   // 2 MiB per 256-row block
    if (maxb < 1) maxb = 1;
    if (maxb > TOTB256) maxb = TOTB256;
    int nch = (TOTB256 + maxb - 1) / maxb;

    k_router<<<N_TOK / 4, 256, 0, stream>>>(x, w_r, cw, xb);
    k_build<<<1, 256, 0, stream>>>(cw, rowlist, cwg, pos2, meta);

    k_tconv<<<dim3(FF_DIM / 64, C_DIM / 64, NE), 256, 0, stream>>>(w_g, wgut, C_DIM, FF_DIM, (size_t)2 * C_DIM * FF_DIM, 1, 0);
    k_tconv<<<dim3(FF_DIM / 64, C_DIM / 64, NE), 256, 0, stream>>>(w_u, wgut, C_DIM, FF_DIM, (size_t)2 * C_DIM * FF_DIM, 1, 16);
    k_tconv<<<dim3(C_DIM / 64, FF_DIM / 64, NE), 256, 0, stream>>>(w_d, wdt, FF_DIM, C_DIM, (size_t)C_DIM * FF_DIM, 0, 0);

    for (int c = 0; c < nch; ++c) {
        int cb = c * maxb;
        int nb = (TOTB256 - cb) < maxb ? (TOTB256 - cb) : maxb;
        k_gateup<<<dim3(2 * FF_DIM / 256, nb), 512, 8 * SLOT_E * 2, stream>>>(xb, wgut, rowlist, meta, h, cb * 256);
        k_down<<<dim3(C_DIM / 128, nb), 512, 3 * D_PAIR * 2, stream>>>(h, wdt, cwg, meta, yd, cb * 256);
    }
    k_combine<<<N_TOK, 256, 0, stream>>>(yd, pos2, out);
}